// Round 1
// baseline (2332.709 us; speedup 1.0000x reference)
//
#include <hip/hip_runtime.h>
#include <math.h>

#define NN 50000
#define EE 800000
#define DIN 128
#define F1 256          // HEADS*HID
#define NHEAD 4
#define CH 64
#define NEG_SLOPE 0.2f

// ---------- float <-> ordered-uint for atomicMax on floats ----------
__device__ __forceinline__ unsigned f2ord(float f) {
    unsigned u = __float_as_uint(f);
    return (u & 0x80000000u) ? ~u : (u | 0x80000000u);
}
__device__ __forceinline__ float ord2f(unsigned o) {
    unsigned u = (o & 0x80000000u) ? (o & 0x7fffffffu) : ~o;
    return __uint_as_float(u);
}

// ---------- tiled fp32 GEMM:  C[M,Ncols] = A[M,K] @ W[K,Ncols] + bias ----------
#define BM 64
#define BN 64
#define BK 16
__global__ __launch_bounds__(256) void gemm_bias(
        const float* __restrict__ A, const float* __restrict__ W,
        const float* __restrict__ bias, float* __restrict__ Cout,
        int M, int K, int Ncols) {
    __shared__ float As[BK][BM + 1];
    __shared__ float Ws[BK][BN + 1];
    const int tid = threadIdx.x;
    const int tx = tid & 15;        // 0..15  (col group)
    const int ty = tid >> 4;        // 0..15  (row group)
    const int row0 = blockIdx.x * BM;
    const int col0 = blockIdx.y * BN;

    float acc[4][4] = {};
    for (int k0 = 0; k0 < K; k0 += BK) {
        #pragma unroll
        for (int j = 0; j < 4; j++) {
            int i = tid + 256 * j;          // 0..1023
            int r = i >> 4, c = i & 15;     // A tile 64x16
            int gr = row0 + r;
            As[c][r] = (gr < M) ? A[(size_t)gr * K + k0 + c] : 0.0f;
        }
        #pragma unroll
        for (int j = 0; j < 4; j++) {
            int i = tid + 256 * j;
            int r = i >> 6, c = i & 63;     // W tile 16x64
            Ws[r][c] = W[(size_t)(k0 + r) * Ncols + col0 + c];
        }
        __syncthreads();
        #pragma unroll
        for (int kk = 0; kk < BK; kk++) {
            float a[4], b[4];
            #pragma unroll
            for (int i = 0; i < 4; i++) a[i] = As[kk][ty * 4 + i];
            #pragma unroll
            for (int j = 0; j < 4; j++) b[j] = Ws[kk][tx * 4 + j];
            #pragma unroll
            for (int i = 0; i < 4; i++)
                #pragma unroll
                for (int j = 0; j < 4; j++) acc[i][j] += a[i] * b[j];
        }
        __syncthreads();
    }
    #pragma unroll
    for (int i = 0; i < 4; i++) {
        int gr = row0 + ty * 4 + i;
        if (gr >= M) continue;
        #pragma unroll
        for (int j = 0; j < 4; j++) {
            int gc = col0 + tx * 4 + j;
            Cout[(size_t)gr * Ncols + gc] = acc[i][j] + bias[gc];
        }
    }
}

// ---------- per-edge attention logits + segment max ----------
// one wave (64 lanes) per edge; lane = channel, 4 heads per lane
__global__ __launch_bounds__(256) void edge_logits(
        const float* __restrict__ xl, const float* __restrict__ xr,
        const int* __restrict__ src, const int* __restrict__ dst,
        const float* __restrict__ att,
        float* __restrict__ logit, unsigned* __restrict__ segmax) {
    int e = blockIdx.x * 4 + (threadIdx.x >> 6);
    int lane = threadIdx.x & 63;
    if (e >= EE) return;
    int s = src[e], d = dst[e];
    const float* pl = xl + (size_t)s * F1;
    const float* pr = xr + (size_t)d * F1;
    float a0, a1, a2, a3;
    {
        float v;
        v = pl[0 * 64 + lane] + pr[0 * 64 + lane]; v = v > 0.f ? v : NEG_SLOPE * v; a0 = v * att[0 * 64 + lane];
        v = pl[1 * 64 + lane] + pr[1 * 64 + lane]; v = v > 0.f ? v : NEG_SLOPE * v; a1 = v * att[1 * 64 + lane];
        v = pl[2 * 64 + lane] + pr[2 * 64 + lane]; v = v > 0.f ? v : NEG_SLOPE * v; a2 = v * att[2 * 64 + lane];
        v = pl[3 * 64 + lane] + pr[3 * 64 + lane]; v = v > 0.f ? v : NEG_SLOPE * v; a3 = v * att[3 * 64 + lane];
    }
    #pragma unroll
    for (int off = 32; off; off >>= 1) {
        a0 += __shfl_xor(a0, off, 64);
        a1 += __shfl_xor(a1, off, 64);
        a2 += __shfl_xor(a2, off, 64);
        a3 += __shfl_xor(a3, off, 64);
    }
    if (lane == 0) {
        logit[(size_t)e * 4 + 0] = a0; atomicMax(&segmax[(size_t)d * 4 + 0], f2ord(a0));
        logit[(size_t)e * 4 + 1] = a1; atomicMax(&segmax[(size_t)d * 4 + 1], f2ord(a1));
        logit[(size_t)e * 4 + 2] = a2; atomicMax(&segmax[(size_t)d * 4 + 2], f2ord(a2));
        logit[(size_t)e * 4 + 3] = a3; atomicMax(&segmax[(size_t)d * 4 + 3], f2ord(a3));
    }
}

// ---------- p = exp(logit - max[dst]); denom[dst] += p ----------
__global__ __launch_bounds__(256) void softmax_norm(
        float* __restrict__ logit_p, const unsigned* __restrict__ segmax,
        const int* __restrict__ dst, float* __restrict__ denom) {
    int i = blockIdx.x * 256 + threadIdx.x;     // over EE*4
    if (i >= EE * 4) return;
    int e = i >> 2, h = i & 3;
    int d = dst[e];
    float m = ord2f(segmax[(size_t)d * 4 + h]);
    float p = __expf(logit_p[i] - m);
    logit_p[i] = p;
    atomicAdd(&denom[(size_t)d * 4 + h], p);
}

// ---------- out[dst] += (p/denom[dst]) * xl[src] ----------
__global__ __launch_bounds__(256) void edge_aggregate(
        const float* __restrict__ p, const float* __restrict__ denom,
        const float* __restrict__ xl,
        const int* __restrict__ src, const int* __restrict__ dst,
        float* __restrict__ out) {
    int e = blockIdx.x * 4 + (threadIdx.x >> 6);
    int lane = threadIdx.x & 63;
    if (e >= EE) return;
    int s = src[e], d = dst[e];
    const float* pl = xl + (size_t)s * F1;
    float* po = out + (size_t)d * F1;
    #pragma unroll
    for (int h = 0; h < 4; h++) {
        float alpha = p[(size_t)e * 4 + h] / denom[(size_t)d * 4 + h];
        atomicAdd(&po[h * 64 + lane], alpha * pl[h * 64 + lane]);
    }
}

// ---------- h = relu(agg + bias) in place ----------
__global__ __launch_bounds__(256) void bias_relu(
        float* __restrict__ C, const float* __restrict__ bias) {
    size_t i = (size_t)blockIdx.x * 256 + threadIdx.x;
    if (i >= (size_t)NN * F1) return;
    float v = C[i] + bias[i & (F1 - 1)];
    C[i] = v > 0.f ? v : 0.f;
}

// ---------- final: mean over heads + bias2, then @ Wout + bout ----------
__global__ __launch_bounds__(256) void final_out(
        const float* __restrict__ agg, const float* __restrict__ bias2,
        const float* __restrict__ Wout, const float* __restrict__ bout,
        float* __restrict__ out) {
    int node = blockIdx.x * 4 + (threadIdx.x >> 6);
    int lane = threadIdx.x & 63;
    if (node >= NN) return;
    const float* pa = agg + (size_t)node * F1;
    float t = 0.25f * (pa[lane] + pa[64 + lane] + pa[128 + lane] + pa[192 + lane]) + bias2[lane];
    float o0 = t * Wout[lane * 2 + 0];
    float o1 = t * Wout[lane * 2 + 1];
    #pragma unroll
    for (int off = 32; off; off >>= 1) {
        o0 += __shfl_xor(o0, off, 64);
        o1 += __shfl_xor(o1, off, 64);
    }
    if (lane == 0) {
        out[(size_t)node * 2 + 0] = o0 + bout[0];
        out[(size_t)node * 2 + 1] = o1 + bout[1];
    }
}

extern "C" void kernel_launch(void* const* d_in, const int* in_sizes, int n_in,
                              void* d_out, int out_size, void* d_ws, size_t ws_size,
                              hipStream_t stream) {
    const float* x     = (const float*)d_in[0];
    const int*   ei    = (const int*)d_in[1];
    const float* Wl1   = (const float*)d_in[2];
    const float* bl1   = (const float*)d_in[3];
    const float* Wr1   = (const float*)d_in[4];
    const float* br1   = (const float*)d_in[5];
    const float* att1  = (const float*)d_in[6];
    const float* bias1 = (const float*)d_in[7];
    const float* Wl2   = (const float*)d_in[8];
    const float* bl2   = (const float*)d_in[9];
    const float* Wr2   = (const float*)d_in[10];
    const float* br2   = (const float*)d_in[11];
    const float* att2  = (const float*)d_in[12];
    const float* bias2 = (const float*)d_in[13];
    const float* Wout  = (const float*)d_in[14];
    const float* bout  = (const float*)d_in[15];

    const int* src = ei;            // edge_index[0]
    const int* dst = ei + EE;       // edge_index[1]

    // workspace layout (floats)
    const size_t NF = (size_t)NN * F1;          // 12.8M
    float*    A   = (float*)d_ws;               // xl   [N,256]
    float*    B   = A + NF;                     // xr   [N,256]
    float*    Cb  = B + NF;                     // agg/h [N,256]
    float*    L   = Cb + NF;                    // logits/p [E,4]
    unsigned* Mx  = (unsigned*)(L + (size_t)EE * 4);   // segmax [N,4]
    float*    Dn  = (float*)(Mx + (size_t)NN * 4);     // denom  [N,4]

    dim3 gemmGrid((NN + BM - 1) / BM, F1 / BN);
    const int edgeBlocks = (EE + 3) / 4;
    const int ehBlocks = (EE * 4 + 255) / 256;
    const int ncBlocks = (int)((NF + 255) / 256);
    const int nodeBlocks = (NN + 3) / 4;

    // ---------------- layer 1 ----------------
    gemm_bias<<<gemmGrid, 256, 0, stream>>>(x, Wl1, bl1, A, NN, DIN, F1);
    gemm_bias<<<gemmGrid, 256, 0, stream>>>(x, Wr1, br1, B, NN, DIN, F1);

    hipMemsetAsync(Mx, 0, (size_t)NN * 4 * sizeof(unsigned), stream);
    edge_logits<<<edgeBlocks, 256, 0, stream>>>(A, B, src, dst, att1, L, Mx);

    hipMemsetAsync(Dn, 0, (size_t)NN * 4 * sizeof(float), stream);
    softmax_norm<<<ehBlocks, 256, 0, stream>>>(L, Mx, dst, Dn);

    hipMemsetAsync(Cb, 0, NF * sizeof(float), stream);
    edge_aggregate<<<edgeBlocks, 256, 0, stream>>>(L, Dn, A, src, dst, Cb);

    bias_relu<<<ncBlocks, 256, 0, stream>>>(Cb, bias1);

    // ---------------- layer 2 ----------------
    gemm_bias<<<gemmGrid, 256, 0, stream>>>(Cb, Wl2, bl2, A, NN, F1, F1);
    gemm_bias<<<gemmGrid, 256, 0, stream>>>(Cb, Wr2, br2, B, NN, F1, F1);

    hipMemsetAsync(Mx, 0, (size_t)NN * 4 * sizeof(unsigned), stream);
    edge_logits<<<edgeBlocks, 256, 0, stream>>>(A, B, src, dst, att2, L, Mx);

    hipMemsetAsync(Dn, 0, (size_t)NN * 4 * sizeof(float), stream);
    softmax_norm<<<ehBlocks, 256, 0, stream>>>(L, Mx, dst, Dn);

    hipMemsetAsync(Cb, 0, NF * sizeof(float), stream);
    edge_aggregate<<<edgeBlocks, 256, 0, stream>>>(L, Dn, A, src, dst, Cb);

    final_out<<<nodeBlocks, 256, 0, stream>>>(Cb, bias2, Wout, bout, (float*)d_out);
}

// Round 2
// 813.304 us; speedup vs baseline: 2.8682x; 2.8682x over previous
//
#include <hip/hip_runtime.h>
#include <math.h>

#define NN 50000
#define EE 800000
#define DIN 128
#define F1 256          // HEADS*HID
#define NEG_SLOPE 0.2f

// ================= tiled fp32 GEMM:  C[M,Ncols] = A[M,K] @ W[K,Ncols] + bias =================
#define BM 64
#define BN 64
#define BK 16
__global__ __launch_bounds__(256) void gemm_bias(
        const float* __restrict__ A, const float* __restrict__ W,
        const float* __restrict__ bias, float* __restrict__ Cout,
        int M, int K, int Ncols) {
    __shared__ float As[BK][BM + 1];
    __shared__ float Ws[BK][BN + 1];
    const int tid = threadIdx.x;
    const int tx = tid & 15;
    const int ty = tid >> 4;
    const int row0 = blockIdx.x * BM;
    const int col0 = blockIdx.y * BN;

    float acc[4][4] = {};
    for (int k0 = 0; k0 < K; k0 += BK) {
        #pragma unroll
        for (int j = 0; j < 4; j++) {
            int i = tid + 256 * j;
            int r = i >> 4, c = i & 15;
            int gr = row0 + r;
            As[c][r] = (gr < M) ? A[(size_t)gr * K + k0 + c] : 0.0f;
        }
        #pragma unroll
        for (int j = 0; j < 4; j++) {
            int i = tid + 256 * j;
            int r = i >> 6, c = i & 63;
            Ws[r][c] = W[(size_t)(k0 + r) * Ncols + col0 + c];
        }
        __syncthreads();
        #pragma unroll
        for (int kk = 0; kk < BK; kk++) {
            float a[4], b[4];
            #pragma unroll
            for (int i = 0; i < 4; i++) a[i] = As[kk][ty * 4 + i];
            #pragma unroll
            for (int j = 0; j < 4; j++) b[j] = Ws[kk][tx * 4 + j];
            #pragma unroll
            for (int i = 0; i < 4; i++)
                #pragma unroll
                for (int j = 0; j < 4; j++) acc[i][j] += a[i] * b[j];
        }
        __syncthreads();
    }
    #pragma unroll
    for (int i = 0; i < 4; i++) {
        int gr = row0 + ty * 4 + i;
        if (gr >= M) continue;
        #pragma unroll
        for (int j = 0; j < 4; j++) {
            int gc = col0 + tx * 4 + j;
            Cout[(size_t)gr * Ncols + gc] = acc[i][j] + bias[gc];
        }
    }
}

// ================= CSR build =================
__global__ __launch_bounds__(256) void count_deg(
        const int* __restrict__ dst, int* __restrict__ deg) {
    int e = blockIdx.x * 256 + threadIdx.x;
    if (e < EE) atomicAdd(&deg[dst[e]], 1);
}

// per-block inclusive scan (Hillis-Steele), block=256
__global__ __launch_bounds__(256) void scanA(
        const int* __restrict__ deg, int* __restrict__ inc, int* __restrict__ bsum) {
    __shared__ int s[256];
    int i = blockIdx.x * 256 + threadIdx.x;
    int v = (i < NN) ? deg[i] : 0;
    s[threadIdx.x] = v;
    __syncthreads();
    #pragma unroll
    for (int off = 1; off < 256; off <<= 1) {
        int t = (threadIdx.x >= off) ? s[threadIdx.x - off] : 0;
        __syncthreads();
        s[threadIdx.x] += t;
        __syncthreads();
    }
    if (i < NN) inc[i] = s[threadIdx.x];
    if (threadIdx.x == 255) bsum[blockIdx.x] = s[255];
}

// single-block exclusive scan of block sums (nblocks <= 256)
__global__ __launch_bounds__(256) void scanB(
        const int* __restrict__ bsum, int* __restrict__ boff, int nblocks) {
    __shared__ int s[256];
    int v = (threadIdx.x < nblocks) ? bsum[threadIdx.x] : 0;
    s[threadIdx.x] = v;
    __syncthreads();
    #pragma unroll
    for (int off = 1; off < 256; off <<= 1) {
        int t = (threadIdx.x >= off) ? s[threadIdx.x - off] : 0;
        __syncthreads();
        s[threadIdx.x] += t;
        __syncthreads();
    }
    if (threadIdx.x < nblocks) boff[threadIdx.x] = s[threadIdx.x] - v;  // exclusive
}

__global__ __launch_bounds__(256) void scanC(
        const int* __restrict__ deg, const int* __restrict__ inc,
        const int* __restrict__ boff,
        int* __restrict__ rowptr, int* __restrict__ wptr) {
    int i = blockIdx.x * 256 + threadIdx.x;
    if (i < NN) {
        int ex = inc[i] - deg[i] + boff[i >> 8];
        rowptr[i] = ex;
        wptr[i] = ex;
    } else if (i == NN) {
        rowptr[NN] = EE;
    }
}

__global__ __launch_bounds__(256) void scatter_src(
        const int* __restrict__ src, const int* __restrict__ dst,
        int* __restrict__ wptr, int* __restrict__ ssrc) {
    int e = blockIdx.x * 256 + threadIdx.x;
    if (e < EE) {
        int pos = atomicAdd(&wptr[dst[e]], 1);
        ssrc[pos] = src[e];
    }
}

// ================= fused GATv2 node kernel =================
// One wave per destination node. Lane owns channels 4*lane..4*lane+3
// (all belonging to head lane>>4). Online softmax over the node's edges.
// Writes normalized aggregation over xr_out[node] (each xr row is read
// only by its own wave, before the write -> safe in-place).
__global__ __launch_bounds__(256) void gat_node(
        const float* __restrict__ xl, float* xr_out,
        const float* __restrict__ att,
        const int* __restrict__ rowptr, const int* __restrict__ ssrc) {
    int node = blockIdx.x * 4 + (threadIdx.x >> 6);
    int lane = threadIdx.x & 63;
    if (node >= NN) return;

    const int beg = rowptr[node];
    const int end = rowptr[node + 1];

    float4 rr = *(const float4*)(xr_out + (size_t)node * F1 + lane * 4);
    float4 at = *(const float4*)(att + lane * 4);

    float m = -INFINITY;
    float den = 0.0f;
    float acc0 = 0.f, acc1 = 0.f, acc2 = 0.f, acc3 = 0.f;

    int s_next = (beg < end) ? ssrc[beg] : 0;
    for (int i = beg; i < end; i++) {
        int s = s_next;
        if (i + 1 < end) s_next = ssrc[i + 1];
        float4 xv = *(const float4*)(xl + (size_t)s * F1 + lane * 4);

        // per-channel LeakyReLU(xl+xr) * att, partial dot
        float v0 = xv.x + rr.x; v0 = v0 > 0.f ? v0 : NEG_SLOPE * v0;
        float v1 = xv.y + rr.y; v1 = v1 > 0.f ? v1 : NEG_SLOPE * v1;
        float v2 = xv.z + rr.z; v2 = v2 > 0.f ? v2 : NEG_SLOPE * v2;
        float v3 = xv.w + rr.w; v3 = v3 > 0.f ? v3 : NEG_SLOPE * v3;
        float part = v0 * at.x + v1 * at.y + v2 * at.z + v3 * at.w;

        // reduce over the 16 lanes of this head (lanes h*16..h*16+15)
        part += __shfl_xor(part, 1, 64);
        part += __shfl_xor(part, 2, 64);
        part += __shfl_xor(part, 4, 64);
        part += __shfl_xor(part, 8, 64);
        float lg = part;   // head-h logit, identical in all 16 lanes of group

        // online softmax update
        float p;
        if (lg > m) {
            float scale = __expf(m - lg);   // exp(-inf)=0 on first edge
            acc0 *= scale; acc1 *= scale; acc2 *= scale; acc3 *= scale;
            den *= scale;
            m = lg;
            p = 1.0f;
        } else {
            p = __expf(lg - m);
        }
        den += p;
        acc0 += p * xv.x; acc1 += p * xv.y; acc2 += p * xv.z; acc3 += p * xv.w;
    }

    float inv = den > 0.f ? 1.0f / den : 0.0f;
    float4 outv = make_float4(acc0 * inv, acc1 * inv, acc2 * inv, acc3 * inv);
    *(float4*)(xr_out + (size_t)node * F1 + lane * 4) = outv;
}

// ================= h = relu(agg + bias) in place =================
__global__ __launch_bounds__(256) void bias_relu(
        float* __restrict__ C, const float* __restrict__ bias) {
    size_t i = (size_t)blockIdx.x * 256 + threadIdx.x;
    if (i >= (size_t)NN * F1) return;
    float v = C[i] + bias[i & (F1 - 1)];
    C[i] = v > 0.f ? v : 0.f;
}

// ================= final: mean over heads + bias2, then @ Wout + bout =================
__global__ __launch_bounds__(256) void final_out(
        const float* __restrict__ agg, const float* __restrict__ bias2,
        const float* __restrict__ Wout, const float* __restrict__ bout,
        float* __restrict__ out) {
    int node = blockIdx.x * 4 + (threadIdx.x >> 6);
    int lane = threadIdx.x & 63;
    if (node >= NN) return;
    const float* pa = agg + (size_t)node * F1;
    float t = 0.25f * (pa[lane] + pa[64 + lane] + pa[128 + lane] + pa[192 + lane]) + bias2[lane];
    float o0 = t * Wout[lane * 2 + 0];
    float o1 = t * Wout[lane * 2 + 1];
    #pragma unroll
    for (int off = 32; off; off >>= 1) {
        o0 += __shfl_xor(o0, off, 64);
        o1 += __shfl_xor(o1, off, 64);
    }
    if (lane == 0) {
        out[(size_t)node * 2 + 0] = o0 + bout[0];
        out[(size_t)node * 2 + 1] = o1 + bout[1];
    }
}

extern "C" void kernel_launch(void* const* d_in, const int* in_sizes, int n_in,
                              void* d_out, int out_size, void* d_ws, size_t ws_size,
                              hipStream_t stream) {
    const float* x     = (const float*)d_in[0];
    const int*   ei    = (const int*)d_in[1];
    const float* Wl1   = (const float*)d_in[2];
    const float* bl1   = (const float*)d_in[3];
    const float* Wr1   = (const float*)d_in[4];
    const float* br1   = (const float*)d_in[5];
    const float* att1  = (const float*)d_in[6];
    const float* bias1 = (const float*)d_in[7];
    const float* Wl2   = (const float*)d_in[8];
    const float* bl2   = (const float*)d_in[9];
    const float* Wr2   = (const float*)d_in[10];
    const float* br2   = (const float*)d_in[11];
    const float* att2  = (const float*)d_in[12];
    const float* bias2 = (const float*)d_in[13];
    const float* Wout  = (const float*)d_in[14];
    const float* bout  = (const float*)d_in[15];

    const int* src = ei;
    const int* dst = ei + EE;

    // ---------- workspace layout ----------
    const size_t NF = (size_t)NN * F1;           // 12.8M floats
    float* A  = (float*)d_ws;                    // xl buffer [N,256]
    float* B  = A + NF;                          // xr/out buffer layer1 [N,256]
    float* Cb = B + NF;                          // xr/out buffer layer2 [N,256]
    int* deg    = (int*)(Cb + NF);
    int* inc    = deg + NN;
    int* rowptr = inc + NN;                      // NN+1
    int* wptr   = rowptr + NN + 1;
    int* ssrc   = wptr + NN;                     // E
    int* bsum   = ssrc + EE;                     // 256
    int* boff   = bsum + 256;                    // 256

    const int scanBlocks = (NN + 255) / 256;     // 196
    const int edgeBlocks = (EE + 255) / 256;     // 3125
    const int nodeBlocks = (NN + 3) / 4;         // 12500
    const int ncBlocks   = (int)((NF + 255) / 256);
    dim3 gemmGrid((NN + BM - 1) / BM, F1 / BN);

    // ---------- CSR build (once; shared by both layers) ----------
    hipMemsetAsync(deg, 0, NN * sizeof(int), stream);
    count_deg<<<edgeBlocks, 256, 0, stream>>>(dst, deg);
    scanA<<<scanBlocks, 256, 0, stream>>>(deg, inc, bsum);
    scanB<<<1, 256, 0, stream>>>(bsum, boff, scanBlocks);
    scanC<<<scanBlocks + 1, 256, 0, stream>>>(deg, inc, boff, rowptr, wptr);
    scatter_src<<<edgeBlocks, 256, 0, stream>>>(src, dst, wptr, ssrc);

    // ---------- layer 1 ----------
    gemm_bias<<<gemmGrid, 256, 0, stream>>>(x, Wl1, bl1, A, NN, DIN, F1);
    gemm_bias<<<gemmGrid, 256, 0, stream>>>(x, Wr1, br1, B, NN, DIN, F1);
    gat_node<<<nodeBlocks, 256, 0, stream>>>(A, B, att1, rowptr, ssrc);
    bias_relu<<<ncBlocks, 256, 0, stream>>>(B, bias1);

    // ---------- layer 2 ----------
    gemm_bias<<<gemmGrid, 256, 0, stream>>>(B, Wl2, bl2, A, NN, F1, F1);
    gemm_bias<<<gemmGrid, 256, 0, stream>>>(B, Wr2, br2, Cb, NN, F1, F1);
    gat_node<<<nodeBlocks, 256, 0, stream>>>(A, Cb, att2, rowptr, ssrc);

    final_out<<<nodeBlocks, 256, 0, stream>>>(Cb, bias2, Wout, bout, (float*)d_out);
}

// Round 4
// 491.835 us; speedup vs baseline: 4.7429x; 1.6536x over previous
//
#include <hip/hip_runtime.h>
#include <math.h>

#define NN 50000
#define EE 800000
#define DIN 128
#define F1 256          // HEADS*HID
#define NEG_SLOPE 0.2f

typedef __bf16 bf16x8 __attribute__((ext_vector_type(8)));
typedef float f32x4 __attribute__((ext_vector_type(4)));

__device__ __forceinline__ ushort f2bf(float f) {
    unsigned u = __float_as_uint(f);
    unsigned r = (u + 0x7FFFu + ((u >> 16) & 1u)) >> 16;   // RNE
    return (ushort)r;
}

__device__ __forceinline__ void gload16(const void* g, void* l) {
    __builtin_amdgcn_global_load_lds(
        (const __attribute__((address_space(1))) void*)g,
        (__attribute__((address_space(3))) void*)l, 16, 0, 0);
}

// ================= converts =================
__global__ __launch_bounds__(256) void cvt_bf16(
        const float* __restrict__ in, ushort* __restrict__ out, int n4) {
    int i = blockIdx.x * 256 + threadIdx.x;
    if (i >= n4) return;
    float4 v = *(const float4*)(in + (size_t)i * 4);
    ushort4 o;
    o.x = f2bf(v.x); o.y = f2bf(v.y); o.z = f2bf(v.z); o.w = f2bf(v.w);
    *(ushort4*)(out + (size_t)i * 4) = o;
}

// Wt[n][k] = bf16(W[k][n]);  W is [K][256]
__global__ __launch_bounds__(256) void cvtT(
        const float* __restrict__ W, ushort* __restrict__ Wt, int K) {
    int idx = blockIdx.x * 256 + threadIdx.x;
    if (idx >= K * 256) return;
    int n = idx / K, k = idx - n * K;
    Wt[idx] = f2bf(W[(size_t)k * 256 + n]);
}

// ================= bf16 MFMA GEMM: C[M,256] = A[M,K] @ Wt^T + bias =================
// A bf16 row-major [M][K]; Wt bf16 [256][K] (pre-transposed); C fp32 [M][256]
__global__ __launch_bounds__(256) void gemm_mfma(
        const ushort* __restrict__ Abf, const ushort* __restrict__ Wt,
        const float* __restrict__ bias, float* __restrict__ Cout,
        int M, int K) {
    __shared__ ushort As[128 * 32];   // [row][slot*8]  (slot-rotated)
    __shared__ ushort Ws[128 * 32];   // [col][slot*8]
    const int tid = threadIdx.x;
    const int wave = tid >> 6, lane = tid & 63;
    const int row0 = blockIdx.x * 128;
    const int col0 = blockIdx.y * 128;
    const int wr = wave >> 1, wc = wave & 1;
    const int g = lane >> 4, lr = lane & 15;

    f32x4 acc[4][4];
    #pragma unroll
    for (int m = 0; m < 4; m++)
        #pragma unroll
        for (int n = 0; n < 4; n++) acc[m][n] = (f32x4){0.f, 0.f, 0.f, 0.f};

    for (int k0 = 0; k0 < K; k0 += 32) {
        #pragma unroll
        for (int j = 0; j < 2; j++) {
            int cc = j * 256 + wave * 64 + lane;       // 0..511, 8 ushorts each
            int rr = cc >> 2;
            int kp = ((cc & 3) - (rr >> 1)) & 3;       // slot rotation (stage side)
            int gr = row0 + rr; if (gr >= M) gr = M - 1;
            gload16(Abf + (size_t)gr * K + k0 + kp * 8, &As[(j * 256 + wave * 64) * 8]);
            gload16(Wt + (size_t)(col0 + rr) * K + k0 + kp * 8, &Ws[(j * 256 + wave * 64) * 8]);
        }
        __syncthreads();
        bf16x8 af[4], bfr[4];
        #pragma unroll
        for (int m = 0; m < 4; m++) {
            int row = wr * 64 + m * 16 + lr;
            int slot = (g + (row >> 1)) & 3;           // rotation (read side)
            af[m] = *(const bf16x8*)&As[(row * 4 + slot) * 8];
        }
        #pragma unroll
        for (int n = 0; n < 4; n++) {
            int col = wc * 64 + n * 16 + lr;
            int slot = (g + (col >> 1)) & 3;
            bfr[n] = *(const bf16x8*)&Ws[(col * 4 + slot) * 8];
        }
        #pragma unroll
        for (int m = 0; m < 4; m++)
            #pragma unroll
            for (int n = 0; n < 4; n++)
                acc[m][n] = __builtin_amdgcn_mfma_f32_16x16x32_bf16(af[m], bfr[n], acc[m][n], 0, 0, 0);
        __syncthreads();
    }
    #pragma unroll
    for (int m = 0; m < 4; m++) {
        int rowb = row0 + wr * 64 + m * 16 + g * 4;
        #pragma unroll
        for (int n = 0; n < 4; n++) {
            int col = col0 + wc * 64 + n * 16 + lr;
            float b = bias[col];
            #pragma unroll
            for (int j = 0; j < 4; j++) {
                int grow = rowb + j;
                if (grow < M) Cout[(size_t)grow * 256 + col] = acc[m][n][j] + b;
            }
        }
    }
}

// ================= CSR build =================
__global__ __launch_bounds__(256) void count_deg(
        const int* __restrict__ dst, int* __restrict__ deg) {
    int e = blockIdx.x * 256 + threadIdx.x;
    if (e < EE) atomicAdd(&deg[dst[e]], 1);
}

__global__ __launch_bounds__(256) void scanA(
        const int* __restrict__ deg, int* __restrict__ inc, int* __restrict__ bsum) {
    __shared__ int s[256];
    int i = blockIdx.x * 256 + threadIdx.x;
    int v = (i < NN) ? deg[i] : 0;
    s[threadIdx.x] = v;
    __syncthreads();
    #pragma unroll
    for (int off = 1; off < 256; off <<= 1) {
        int t = (threadIdx.x >= off) ? s[threadIdx.x - off] : 0;
        __syncthreads();
        s[threadIdx.x] += t;
        __syncthreads();
    }
    if (i < NN) inc[i] = s[threadIdx.x];
    if (threadIdx.x == 255) bsum[blockIdx.x] = s[255];
}

__global__ __launch_bounds__(256) void scanB(
        const int* __restrict__ bsum, int* __restrict__ boff, int nblocks) {
    __shared__ int s[256];
    int v = (threadIdx.x < nblocks) ? bsum[threadIdx.x] : 0;
    s[threadIdx.x] = v;
    __syncthreads();
    #pragma unroll
    for (int off = 1; off < 256; off <<= 1) {
        int t = (threadIdx.x >= off) ? s[threadIdx.x - off] : 0;
        __syncthreads();
        s[threadIdx.x] += t;
        __syncthreads();
    }
    if (threadIdx.x < nblocks) boff[threadIdx.x] = s[threadIdx.x] - v;
}

__global__ __launch_bounds__(256) void scanC(
        const int* __restrict__ deg, const int* __restrict__ inc,
        const int* __restrict__ boff,
        int* __restrict__ rowptr, int* __restrict__ wptr) {
    int i = blockIdx.x * 256 + threadIdx.x;
    if (i < NN) {
        int ex = inc[i] - deg[i] + boff[i >> 8];
        rowptr[i] = ex;
        wptr[i] = ex;
    } else if (i == NN) {
        rowptr[NN] = EE;
    }
}

__global__ __launch_bounds__(256) void scatter_src(
        const int* __restrict__ src, const int* __restrict__ dst,
        int* __restrict__ wptr, int* __restrict__ ssrc) {
    int e = blockIdx.x * 256 + threadIdx.x;
    if (e < EE) {
        int pos = atomicAdd(&wptr[dst[e]], 1);
        ssrc[pos] = src[e];
    }
}

// ================= fused GATv2 node kernel (online softmax) =================
__global__ __launch_bounds__(256) void gat_node(
        const float* __restrict__ xl, float* xr_out,
        const float* __restrict__ att,
        const int* __restrict__ rowptr, const int* __restrict__ ssrc) {
    int node = blockIdx.x * 4 + (threadIdx.x >> 6);
    int lane = threadIdx.x & 63;
    if (node >= NN) return;

    const int beg = rowptr[node];
    const int end = rowptr[node + 1];

    float4 rr = *(const float4*)(xr_out + (size_t)node * F1 + lane * 4);
    float4 at = *(const float4*)(att + lane * 4);

    float m = -INFINITY;
    float den = 0.0f;
    float acc0 = 0.f, acc1 = 0.f, acc2 = 0.f, acc3 = 0.f;

    int s_next = (beg < end) ? ssrc[beg] : 0;
    for (int i = beg; i < end; i++) {
        int s = s_next;
        if (i + 1 < end) s_next = ssrc[i + 1];
        float4 xv = *(const float4*)(xl + (size_t)s * F1 + lane * 4);

        float v0 = xv.x + rr.x; v0 = v0 > 0.f ? v0 : NEG_SLOPE * v0;
        float v1 = xv.y + rr.y; v1 = v1 > 0.f ? v1 : NEG_SLOPE * v1;
        float v2 = xv.z + rr.z; v2 = v2 > 0.f ? v2 : NEG_SLOPE * v2;
        float v3 = xv.w + rr.w; v3 = v3 > 0.f ? v3 : NEG_SLOPE * v3;
        float part = v0 * at.x + v1 * at.y + v2 * at.z + v3 * at.w;

        part += __shfl_xor(part, 1, 64);
        part += __shfl_xor(part, 2, 64);
        part += __shfl_xor(part, 4, 64);
        part += __shfl_xor(part, 8, 64);
        float lg = part;

        float p;
        if (lg > m) {
            float scale = __expf(m - lg);
            acc0 *= scale; acc1 *= scale; acc2 *= scale; acc3 *= scale;
            den *= scale;
            m = lg;
            p = 1.0f;
        } else {
            p = __expf(lg - m);
        }
        den += p;
        acc0 += p * xv.x; acc1 += p * xv.y; acc2 += p * xv.z; acc3 += p * xv.w;
    }

    float inv = den > 0.f ? 1.0f / den : 0.0f;
    float4 outv = make_float4(acc0 * inv, acc1 * inv, acc2 * inv, acc3 * inv);
    *(float4*)(xr_out + (size_t)node * F1 + lane * 4) = outv;
}

// ================= relu(agg + bias) -> bf16 =================
__global__ __launch_bounds__(256) void bias_relu_bf(
        const float* __restrict__ C, const float* __restrict__ bias,
        ushort* __restrict__ out) {
    int i = blockIdx.x * 256 + threadIdx.x;      // over NN*F1/4
    if (i >= NN * F1 / 4) return;
    float4 v = *(const float4*)(C + (size_t)i * 4);
    int cb = (i * 4) & (F1 - 1);
    ushort4 o;
    float t;
    t = v.x + bias[cb + 0]; t = t > 0.f ? t : 0.f; o.x = f2bf(t);
    t = v.y + bias[cb + 1]; t = t > 0.f ? t : 0.f; o.y = f2bf(t);
    t = v.z + bias[cb + 2]; t = t > 0.f ? t : 0.f; o.z = f2bf(t);
    t = v.w + bias[cb + 3]; t = t > 0.f ? t : 0.f; o.w = f2bf(t);
    *(ushort4*)(out + (size_t)i * 4) = o;
}

// ================= final: mean over heads + bias2, then @ Wout + bout =================
__global__ __launch_bounds__(256) void final_out(
        const float* __restrict__ agg, const float* __restrict__ bias2,
        const float* __restrict__ Wout, const float* __restrict__ bout,
        float* __restrict__ out) {
    int node = blockIdx.x * 4 + (threadIdx.x >> 6);
    int lane = threadIdx.x & 63;
    if (node >= NN) return;
    const float* pa = agg + (size_t)node * F1;
    float t = 0.25f * (pa[lane] + pa[64 + lane] + pa[128 + lane] + pa[192 + lane]) + bias2[lane];
    float o0 = t * Wout[lane * 2 + 0];
    float o1 = t * Wout[lane * 2 + 1];
    #pragma unroll
    for (int off = 32; off; off >>= 1) {
        o0 += __shfl_xor(o0, off, 64);
        o1 += __shfl_xor(o1, off, 64);
    }
    if (lane == 0) {
        out[(size_t)node * 2 + 0] = o0 + bout[0];
        out[(size_t)node * 2 + 1] = o1 + bout[1];
    }
}

extern "C" void kernel_launch(void* const* d_in, const int* in_sizes, int n_in,
                              void* d_out, int out_size, void* d_ws, size_t ws_size,
                              hipStream_t stream) {
    const float* x     = (const float*)d_in[0];
    const int*   ei    = (const int*)d_in[1];
    const float* Wl1   = (const float*)d_in[2];
    const float* bl1   = (const float*)d_in[3];
    const float* Wr1   = (const float*)d_in[4];
    const float* br1   = (const float*)d_in[5];
    const float* att1  = (const float*)d_in[6];
    const float* bias1 = (const float*)d_in[7];
    const float* Wl2   = (const float*)d_in[8];
    const float* bl2   = (const float*)d_in[9];
    const float* Wr2   = (const float*)d_in[10];
    const float* br2   = (const float*)d_in[11];
    const float* att2  = (const float*)d_in[12];
    const float* bias2 = (const float*)d_in[13];
    const float* Wout  = (const float*)d_in[14];
    const float* bout  = (const float*)d_in[15];

    const int* src = ei;
    const int* dst = ei + EE;

    // ---------- workspace layout ----------
    const size_t NF = (size_t)NN * F1;                 // 12.8M floats
    float*  A     = (float*)d_ws;                      // [N,256] fp32
    float*  B     = A + NF;                            // [N,256] fp32
    ushort* x_bf  = (ushort*)(B + NF);                 // [N,128] bf16
    ushort* h1_bf = x_bf + (size_t)NN * DIN;           // [N,256] bf16
    ushort* Wtl1  = h1_bf + NF;                        // [256,128]
    ushort* Wtr1  = Wtl1 + 256 * DIN;
    ushort* Wtl2  = Wtr1 + 256 * DIN;                  // [256,256]
    ushort* Wtr2  = Wtl2 + 256 * 256;
    int* deg    = (int*)(Wtr2 + 256 * 256);
    int* inc    = deg + NN;
    int* rowptr = inc + NN;                            // NN+1
    int* wptr   = rowptr + NN + 1;
    int* ssrc   = wptr + NN;                           // E
    int* bsum   = ssrc + EE;                           // 256
    int* boff   = bsum + 256;

    const int scanBlocks = (NN + 255) / 256;
    const int edgeBlocks = (EE + 255) / 256;
    const int nodeBlocks = (NN + 3) / 4;
    dim3 gemmGrid((NN + 127) / 128, 2);

    // ---------- CSR build ----------
    hipMemsetAsync(deg, 0, NN * sizeof(int), stream);
    count_deg<<<edgeBlocks, 256, 0, stream>>>(dst, deg);
    scanA<<<scanBlocks, 256, 0, stream>>>(deg, inc, bsum);
    scanB<<<1, 256, 0, stream>>>(bsum, boff, scanBlocks);
    scanC<<<scanBlocks + 1, 256, 0, stream>>>(deg, inc, boff, rowptr, wptr);
    scatter_src<<<edgeBlocks, 256, 0, stream>>>(src, dst, wptr, ssrc);

    // ---------- converts ----------
    cvt_bf16<<<(NN * DIN / 4 + 255) / 256, 256, 0, stream>>>(x, x_bf, NN * DIN / 4);
    cvtT<<<(DIN * 256 + 255) / 256, 256, 0, stream>>>(Wl1, Wtl1, DIN);
    cvtT<<<(DIN * 256 + 255) / 256, 256, 0, stream>>>(Wr1, Wtr1, DIN);
    cvtT<<<(256 * 256 + 255) / 256, 256, 0, stream>>>(Wl2, Wtl2, 256);
    cvtT<<<(256 * 256 + 255) / 256, 256, 0, stream>>>(Wr2, Wtr2, 256);

    // ---------- layer 1 ----------
    gemm_mfma<<<gemmGrid, 256, 0, stream>>>(x_bf, Wtl1, bl1, A, NN, DIN);
    gemm_mfma<<<gemmGrid, 256, 0, stream>>>(x_bf, Wtr1, br1, B, NN, DIN);
    gat_node<<<nodeBlocks, 256, 0, stream>>>(A, B, att1, rowptr, ssrc);
    bias_relu_bf<<<(NN * F1 / 4 + 255) / 256, 256, 0, stream>>>(B, bias1, h1_bf);

    // ---------- layer 2 ----------
    gemm_mfma<<<gemmGrid, 256, 0, stream>>>(h1_bf, Wtl2, bl2, A, NN, 256);
    gemm_mfma<<<gemmGrid, 256, 0, stream>>>(h1_bf, Wtr2, br2, B, NN, 256);
    gat_node<<<nodeBlocks, 256, 0, stream>>>(A, B, att2, rowptr, ssrc);

    final_out<<<nodeBlocks, 256, 0, stream>>>(B, bias2, Wout, bout, (float*)d_out);
}

// Round 5
// 389.621 us; speedup vs baseline: 5.9871x; 1.2623x over previous
//
#include <hip/hip_runtime.h>
#include <math.h>

#define NN 50000
#define EE 800000
#define DIN 128
#define F1 256          // HEADS*HID
#define NEG_SLOPE 0.2f

typedef __bf16 bf16x8 __attribute__((ext_vector_type(8)));
typedef float f32x4 __attribute__((ext_vector_type(4)));

__device__ __forceinline__ ushort f2bf(float f) {
    unsigned u = __float_as_uint(f);
    unsigned r = (u + 0x7FFFu + ((u >> 16) & 1u)) >> 16;   // RNE
    return (ushort)r;
}

__device__ __forceinline__ void gload16(const void* g, void* l) {
    __builtin_amdgcn_global_load_lds(
        (const __attribute__((address_space(1))) void*)g,
        (__attribute__((address_space(3))) void*)l, 16, 0, 0);
}

// ================= converts =================
__global__ __launch_bounds__(256) void cvt_bf16(
        const float* __restrict__ in, ushort* __restrict__ out, int n4) {
    int i = blockIdx.x * 256 + threadIdx.x;
    if (i >= n4) return;
    float4 v = *(const float4*)(in + (size_t)i * 4);
    ushort4 o;
    o.x = f2bf(v.x); o.y = f2bf(v.y); o.z = f2bf(v.z); o.w = f2bf(v.w);
    *(ushort4*)(out + (size_t)i * 4) = o;
}

// Wt[n][k] = bf16(W[k][n]);  W is [K][256]
__global__ __launch_bounds__(256) void cvtT(
        const float* __restrict__ W, ushort* __restrict__ Wt, int K) {
    int idx = blockIdx.x * 256 + threadIdx.x;
    if (idx >= K * 256) return;
    int n = idx / K, k = idx - n * K;
    Wt[idx] = f2bf(W[(size_t)k * 256 + n]);
}

// ================= bf16 MFMA GEMM: C[M,256] = A[M,K] @ Wt^T + bias =================
// A bf16 row-major [M][K]; Wt bf16 [256][K]; out fp32 or bf16 (obf flag)
__global__ __launch_bounds__(256) void gemm_mfma(
        const ushort* __restrict__ Abf, const ushort* __restrict__ Wt,
        const float* __restrict__ bias, float* __restrict__ Cout,
        ushort* __restrict__ Cbf, int obf, int M, int K) {
    __shared__ ushort As[128 * 32];   // [row][slot*8]  (slot-rotated)
    __shared__ ushort Ws[128 * 32];   // [col][slot*8]
    const int tid = threadIdx.x;
    const int wave = tid >> 6, lane = tid & 63;
    const int row0 = blockIdx.x * 128;
    const int col0 = blockIdx.y * 128;
    const int wr = wave >> 1, wc = wave & 1;
    const int g = lane >> 4, lr = lane & 15;

    f32x4 acc[4][4];
    #pragma unroll
    for (int m = 0; m < 4; m++)
        #pragma unroll
        for (int n = 0; n < 4; n++) acc[m][n] = (f32x4){0.f, 0.f, 0.f, 0.f};

    for (int k0 = 0; k0 < K; k0 += 32) {
        #pragma unroll
        for (int j = 0; j < 2; j++) {
            int cc = j * 256 + wave * 64 + lane;       // 0..511, 8 ushorts each
            int rr = cc >> 2;
            int kp = ((cc & 3) - (rr >> 1)) & 3;       // slot rotation (stage side)
            int gr = row0 + rr; if (gr >= M) gr = M - 1;
            gload16(Abf + (size_t)gr * K + k0 + kp * 8, &As[(j * 256 + wave * 64) * 8]);
            gload16(Wt + (size_t)(col0 + rr) * K + k0 + kp * 8, &Ws[(j * 256 + wave * 64) * 8]);
        }
        __syncthreads();
        bf16x8 af[4], bfr[4];
        #pragma unroll
        for (int m = 0; m < 4; m++) {
            int row = wr * 64 + m * 16 + lr;
            int slot = (g + (row >> 1)) & 3;           // rotation (read side)
            af[m] = *(const bf16x8*)&As[(row * 4 + slot) * 8];
        }
        #pragma unroll
        for (int n = 0; n < 4; n++) {
            int col = wc * 64 + n * 16 + lr;
            int slot = (g + (col >> 1)) & 3;
            bfr[n] = *(const bf16x8*)&Ws[(col * 4 + slot) * 8];
        }
        #pragma unroll
        for (int m = 0; m < 4; m++)
            #pragma unroll
            for (int n = 0; n < 4; n++)
                acc[m][n] = __builtin_amdgcn_mfma_f32_16x16x32_bf16(af[m], bfr[n], acc[m][n], 0, 0, 0);
        __syncthreads();
    }
    #pragma unroll
    for (int m = 0; m < 4; m++) {
        int rowb = row0 + wr * 64 + m * 16 + g * 4;
        #pragma unroll
        for (int n = 0; n < 4; n++) {
            int col = col0 + wc * 64 + n * 16 + lr;
            float b = bias[col];
            #pragma unroll
            for (int j = 0; j < 4; j++) {
                int grow = rowb + j;
                if (grow < M) {
                    float val = acc[m][n][j] + b;
                    if (obf) Cbf[(size_t)grow * 256 + col] = f2bf(val);
                    else     Cout[(size_t)grow * 256 + col] = val;
                }
            }
        }
    }
}

// ================= CSR build =================
__global__ __launch_bounds__(256) void count_deg(
        const int* __restrict__ dst, int* __restrict__ deg) {
    int e = blockIdx.x * 256 + threadIdx.x;
    if (e < EE) atomicAdd(&deg[dst[e]], 1);
}

__global__ __launch_bounds__(256) void scanA(
        const int* __restrict__ deg, int* __restrict__ inc, int* __restrict__ bsum) {
    __shared__ int s[256];
    int i = blockIdx.x * 256 + threadIdx.x;
    int v = (i < NN) ? deg[i] : 0;
    s[threadIdx.x] = v;
    __syncthreads();
    #pragma unroll
    for (int off = 1; off < 256; off <<= 1) {
        int t = (threadIdx.x >= off) ? s[threadIdx.x - off] : 0;
        __syncthreads();
        s[threadIdx.x] += t;
        __syncthreads();
    }
    if (i < NN) inc[i] = s[threadIdx.x];
    if (threadIdx.x == 255) bsum[blockIdx.x] = s[255];
}

__global__ __launch_bounds__(256) void scanB(
        const int* __restrict__ bsum, int* __restrict__ boff, int nblocks) {
    __shared__ int s[256];
    int v = (threadIdx.x < nblocks) ? bsum[threadIdx.x] : 0;
    s[threadIdx.x] = v;
    __syncthreads();
    #pragma unroll
    for (int off = 1; off < 256; off <<= 1) {
        int t = (threadIdx.x >= off) ? s[threadIdx.x - off] : 0;
        __syncthreads();
        s[threadIdx.x] += t;
        __syncthreads();
    }
    if (threadIdx.x < nblocks) boff[threadIdx.x] = s[threadIdx.x] - v;
}

__global__ __launch_bounds__(256) void scanC(
        const int* __restrict__ deg, const int* __restrict__ inc,
        const int* __restrict__ boff,
        int* __restrict__ rowptr, int* __restrict__ wptr) {
    int i = blockIdx.x * 256 + threadIdx.x;
    if (i < NN) {
        int ex = inc[i] - deg[i] + boff[i >> 8];
        rowptr[i] = ex;
        wptr[i] = ex;
    } else if (i == NN) {
        rowptr[NN] = EE;
    }
}

__global__ __launch_bounds__(256) void scatter_src(
        const int* __restrict__ src, const int* __restrict__ dst,
        int* __restrict__ wptr, int* __restrict__ ssrc) {
    int e = blockIdx.x * 256 + threadIdx.x;
    if (e < EE) {
        int pos = atomicAdd(&wptr[dst[e]], 1);
        ssrc[pos] = src[e];
    }
}

// ================= fused GATv2 node kernel =================
// One wave per dst node, split into two 32-lane halves; each half processes
// its own subset of the node's edges (2 edges in flight per iteration).
// Lane owns 8 channels: ch = (lane&31)*8 .. +7 (head = (lane&31)>>3).
// xl is bf16 [N,256]; xr_out fp32 [N,256] read-then-overwritten in place.
__global__ __launch_bounds__(256) void gat_node(
        const ushort* __restrict__ xl, float* xr_out,
        const float* __restrict__ att,
        const int* __restrict__ rowptr, const int* __restrict__ ssrc) {
    int node = blockIdx.x * 4 + (threadIdx.x >> 6);
    int lane = threadIdx.x & 63;
    if (node >= NN) return;
    const int half = lane >> 5;
    const int hl = lane & 31;

    const int beg = rowptr[node];
    const int cnt = rowptr[node + 1] - beg;
    const int cntA = (cnt + 1) >> 1;
    const int mybeg = beg + half * cntA;
    const int mycnt = half ? (cnt - cntA) : cntA;

    // per-lane xr and att (8 channels)
    float rr[8], at[8];
    {
        const float* prr = xr_out + (size_t)node * F1 + hl * 8;
        const float* pat = att + hl * 8;
        #pragma unroll
        for (int k2 = 0; k2 < 2; k2++) {
            float4 t = *(const float4*)(prr + k2 * 4);
            rr[k2 * 4 + 0] = t.x; rr[k2 * 4 + 1] = t.y; rr[k2 * 4 + 2] = t.z; rr[k2 * 4 + 3] = t.w;
            float4 ta = *(const float4*)(pat + k2 * 4);
            at[k2 * 4 + 0] = ta.x; at[k2 * 4 + 1] = ta.y; at[k2 * 4 + 2] = ta.z; at[k2 * 4 + 3] = ta.w;
        }
    }

    float m = -3.0e38f, den = 0.f;
    float acc[8] = {0.f, 0.f, 0.f, 0.f, 0.f, 0.f, 0.f, 0.f};

    int s = (mycnt > 0) ? ssrc[mybeg] : 0;
    for (int it = 0; it < cntA; it++) {
        const bool valid = (it < mycnt);
        const bool validn = (it + 1 < mycnt);
        int s_next = ssrc[mybeg + (validn ? it + 1 : 0)];

        const ushort* ps = xl + (size_t)s * F1 + hl * 8;
        uint4 ud = *(const uint4*)ps;
        float xv[8];
        xv[0] = __uint_as_float(ud.x << 16); xv[1] = __uint_as_float(ud.x & 0xffff0000u);
        xv[2] = __uint_as_float(ud.y << 16); xv[3] = __uint_as_float(ud.y & 0xffff0000u);
        xv[4] = __uint_as_float(ud.z << 16); xv[5] = __uint_as_float(ud.z & 0xffff0000u);
        xv[6] = __uint_as_float(ud.w << 16); xv[7] = __uint_as_float(ud.w & 0xffff0000u);

        float part = 0.f;
        #pragma unroll
        for (int c = 0; c < 8; c++) {
            float v = xv[c] + rr[c];
            float lk = fmaxf(v, NEG_SLOPE * v);      // leaky (slope<1)
            part = fmaf(lk, at[c], part);
        }
        part += __shfl_xor(part, 1, 64);
        part += __shfl_xor(part, 2, 64);
        part += __shfl_xor(part, 4, 64);             // head logit in 8-lane group

        float lg = valid ? part : m;
        float mn = fmaxf(m, lg);
        float corr = __expf(m - mn);
        float p = valid ? __expf(lg - mn) : 0.f;
        den = fmaf(den, corr, p);
        #pragma unroll
        for (int c = 0; c < 8; c++) acc[c] = fmaf(acc[c], corr, p * xv[c]);
        m = mn;
        s = s_next;
    }

    // merge the two half-wave streams
    float m2 = __shfl_xor(m, 32, 64);
    float den2 = __shfl_xor(den, 32, 64);
    float mn = fmaxf(m, m2);
    float cA = __expf(m - mn);
    float cB = __expf(m2 - mn);
    float dtot = fmaf(den, cA, den2 * cB);
    float inv = dtot > 0.f ? 1.0f / dtot : 0.f;
    float o[8];
    #pragma unroll
    for (int c = 0; c < 8; c++) {
        float other = __shfl_xor(acc[c], 32, 64);
        o[c] = fmaf(acc[c], cA, other * cB) * inv;
    }

    // write 16B per lane: half 0 -> ch 0..3, half 1 -> ch 4..7 of this lane's 8
    float4 wv = half ? make_float4(o[4], o[5], o[6], o[7])
                     : make_float4(o[0], o[1], o[2], o[3]);
    *(float4*)(xr_out + (size_t)node * F1 + hl * 8 + half * 4) = wv;
}

// ================= relu(agg + bias) -> bf16 =================
__global__ __launch_bounds__(256) void bias_relu_bf(
        const float* __restrict__ C, const float* __restrict__ bias,
        ushort* __restrict__ out) {
    int i = blockIdx.x * 256 + threadIdx.x;      // over NN*F1/4
    if (i >= NN * F1 / 4) return;
    float4 v = *(const float4*)(C + (size_t)i * 4);
    int cb = (i * 4) & (F1 - 1);
    ushort4 o;
    float t;
    t = v.x + bias[cb + 0]; t = t > 0.f ? t : 0.f; o.x = f2bf(t);
    t = v.y + bias[cb + 1]; t = t > 0.f ? t : 0.f; o.y = f2bf(t);
    t = v.z + bias[cb + 2]; t = t > 0.f ? t : 0.f; o.z = f2bf(t);
    t = v.w + bias[cb + 3]; t = t > 0.f ? t : 0.f; o.w = f2bf(t);
    *(ushort4*)(out + (size_t)i * 4) = o;
}

// ================= final: mean over heads + bias2, then @ Wout + bout =================
__global__ __launch_bounds__(256) void final_out(
        const float* __restrict__ agg, const float* __restrict__ bias2,
        const float* __restrict__ Wout, const float* __restrict__ bout,
        float* __restrict__ out) {
    int node = blockIdx.x * 4 + (threadIdx.x >> 6);
    int lane = threadIdx.x & 63;
    if (node >= NN) return;
    const float* pa = agg + (size_t)node * F1;
    float t = 0.25f * (pa[lane] + pa[64 + lane] + pa[128 + lane] + pa[192 + lane]) + bias2[lane];
    float o0 = t * Wout[lane * 2 + 0];
    float o1 = t * Wout[lane * 2 + 1];
    #pragma unroll
    for (int off = 32; off; off >>= 1) {
        o0 += __shfl_xor(o0, off, 64);
        o1 += __shfl_xor(o1, off, 64);
    }
    if (lane == 0) {
        out[(size_t)node * 2 + 0] = o0 + bout[0];
        out[(size_t)node * 2 + 1] = o1 + bout[1];
    }
}

extern "C" void kernel_launch(void* const* d_in, const int* in_sizes, int n_in,
                              void* d_out, int out_size, void* d_ws, size_t ws_size,
                              hipStream_t stream) {
    const float* x     = (const float*)d_in[0];
    const int*   ei    = (const int*)d_in[1];
    const float* Wl1   = (const float*)d_in[2];
    const float* bl1   = (const float*)d_in[3];
    const float* Wr1   = (const float*)d_in[4];
    const float* br1   = (const float*)d_in[5];
    const float* att1  = (const float*)d_in[6];
    const float* bias1 = (const float*)d_in[7];
    const float* Wl2   = (const float*)d_in[8];
    const float* bl2   = (const float*)d_in[9];
    const float* Wr2   = (const float*)d_in[10];
    const float* br2   = (const float*)d_in[11];
    const float* att2  = (const float*)d_in[12];
    const float* bias2 = (const float*)d_in[13];
    const float* Wout  = (const float*)d_in[14];
    const float* bout  = (const float*)d_in[15];

    const int* src = ei;
    const int* dst = ei + EE;

    // ---------- workspace layout ----------
    const size_t NF = (size_t)NN * F1;                 // 12.8M
    float*  B     = (float*)d_ws;                      // [N,256] fp32 (xr / agg)
    ushort* A_bf  = (ushort*)(B + NF);                 // [N,256] bf16 (xl)
    ushort* x_bf  = A_bf + NF;                         // [N,128] bf16
    ushort* h1_bf = x_bf + (size_t)NN * DIN;           // [N,256] bf16
    ushort* Wtl1  = h1_bf + NF;                        // [256,128]
    ushort* Wtr1  = Wtl1 + 256 * DIN;
    ushort* Wtl2  = Wtr1 + 256 * DIN;                  // [256,256]
    ushort* Wtr2  = Wtl2 + 256 * 256;
    int* deg    = (int*)(Wtr2 + 256 * 256);
    int* inc    = deg + NN;
    int* rowptr = inc + NN;                            // NN+1
    int* wptr   = rowptr + NN + 1;
    int* ssrc   = wptr + NN;                           // E
    int* bsum   = ssrc + EE;                           // 256
    int* boff   = bsum + 256;

    const int scanBlocks = (NN + 255) / 256;
    const int edgeBlocks = (EE + 255) / 256;
    const int nodeBlocks = (NN + 3) / 4;
    dim3 gemmGrid((NN + 127) / 128, 2);

    // ---------- CSR build ----------
    hipMemsetAsync(deg, 0, NN * sizeof(int), stream);
    count_deg<<<edgeBlocks, 256, 0, stream>>>(dst, deg);
    scanA<<<scanBlocks, 256, 0, stream>>>(deg, inc, bsum);
    scanB<<<1, 256, 0, stream>>>(bsum, boff, scanBlocks);
    scanC<<<scanBlocks + 1, 256, 0, stream>>>(deg, inc, boff, rowptr, wptr);
    scatter_src<<<edgeBlocks, 256, 0, stream>>>(src, dst, wptr, ssrc);

    // ---------- converts ----------
    cvt_bf16<<<(NN * DIN / 4 + 255) / 256, 256, 0, stream>>>(x, x_bf, NN * DIN / 4);
    cvtT<<<(DIN * 256 + 255) / 256, 256, 0, stream>>>(Wl1, Wtl1, DIN);
    cvtT<<<(DIN * 256 + 255) / 256, 256, 0, stream>>>(Wr1, Wtr1, DIN);
    cvtT<<<(256 * 256 + 255) / 256, 256, 0, stream>>>(Wl2, Wtl2, 256);
    cvtT<<<(256 * 256 + 255) / 256, 256, 0, stream>>>(Wr2, Wtr2, 256);

    // ---------- layer 1 ----------
    gemm_mfma<<<gemmGrid, 256, 0, stream>>>(x_bf, Wtl1, bl1, nullptr, A_bf, 1, NN, DIN);
    gemm_mfma<<<gemmGrid, 256, 0, stream>>>(x_bf, Wtr1, br1, B, nullptr, 0, NN, DIN);
    gat_node<<<nodeBlocks, 256, 0, stream>>>(A_bf, B, att1, rowptr, ssrc);
    bias_relu_bf<<<(NN * F1 / 4 + 255) / 256, 256, 0, stream>>>(B, bias1, h1_bf);

    // ---------- layer 2 ----------
    gemm_mfma<<<gemmGrid, 256, 0, stream>>>(h1_bf, Wtl2, bl2, nullptr, A_bf, 1, NN, 256);
    gemm_mfma<<<gemmGrid, 256, 0, stream>>>(h1_bf, Wtr2, br2, B, nullptr, 0, NN, 256);
    gat_node<<<nodeBlocks, 256, 0, stream>>>(A_bf, B, att2, rowptr, ssrc);

    final_out<<<nodeBlocks, 256, 0, stream>>>(B, bias2, Wout, bout, (float*)d_out);
}

// Round 6
// 334.703 us; speedup vs baseline: 6.9695x; 1.1641x over previous
//
#include <hip/hip_runtime.h>
#include <math.h>

#define NN 50000
#define EE 800000
#define DIN 128
#define F1 256          // HEADS*HID
#define NEG_SLOPE 0.2f

typedef __bf16 bf16x8 __attribute__((ext_vector_type(8)));
typedef float f32x4 __attribute__((ext_vector_type(4)));

__device__ __forceinline__ ushort f2bf(float f) {
    unsigned u = __float_as_uint(f);
    unsigned r = (u + 0x7FFFu + ((u >> 16) & 1u)) >> 16;   // RNE
    return (ushort)r;
}

__device__ __forceinline__ void gload16(const void* g, void* l) {
    __builtin_amdgcn_global_load_lds(
        (const __attribute__((address_space(1))) void*)g,
        (__attribute__((address_space(3))) void*)l, 16, 0, 0);
}

__device__ __forceinline__ void unpack8(uint4 ud, float* xv) {
    xv[0] = __uint_as_float(ud.x << 16); xv[1] = __uint_as_float(ud.x & 0xffff0000u);
    xv[2] = __uint_as_float(ud.y << 16); xv[3] = __uint_as_float(ud.y & 0xffff0000u);
    xv[4] = __uint_as_float(ud.z << 16); xv[5] = __uint_as_float(ud.z & 0xffff0000u);
    xv[6] = __uint_as_float(ud.w << 16); xv[7] = __uint_as_float(ud.w & 0xffff0000u);
}

// ================= converts =================
__global__ __launch_bounds__(256) void cvt_bf16(
        const float* __restrict__ in, ushort* __restrict__ out, int n4) {
    int i = blockIdx.x * 256 + threadIdx.x;
    if (i >= n4) return;
    float4 v = *(const float4*)(in + (size_t)i * 4);
    ushort4 o;
    o.x = f2bf(v.x); o.y = f2bf(v.y); o.z = f2bf(v.z); o.w = f2bf(v.w);
    *(ushort4*)(out + (size_t)i * 4) = o;
}

// Wt[n][k] = bf16(W[k][n]);  W is [K][256], Wt is [256][K] at given base
__global__ __launch_bounds__(256) void cvtT(
        const float* __restrict__ W, ushort* __restrict__ Wt, int K) {
    int idx = blockIdx.x * 256 + threadIdx.x;
    if (idx >= K * 256) return;
    int n = idx / K, k = idx - n * K;
    Wt[idx] = f2bf(W[(size_t)k * 256 + n]);
}

// ================= fused bf16 MFMA GEMM: C[M,512] = A[M,K] @ [Wl;Wr]^T + bias =================
// A bf16 [M][K]; Wst bf16 [512][K] (stacked, pre-transposed); out bf16 [M][512]
__global__ __launch_bounds__(256) void gemm_mfma2(
        const ushort* __restrict__ Abf, const ushort* __restrict__ Wst,
        const float* __restrict__ biasL, const float* __restrict__ biasR,
        ushort* __restrict__ Cbf, int M, int K) {
    __shared__ ushort As[128 * 32];   // [row][slot*8]  (slot-rotated)
    __shared__ ushort Ws[128 * 32];   // [col][slot*8]
    const int tid = threadIdx.x;
    const int wave = tid >> 6, lane = tid & 63;
    const int row0 = blockIdx.x * 128;
    const int col0 = blockIdx.y * 128;          // 0..3 -> 512 cols
    const int wr = wave >> 1, wc = wave & 1;
    const int g = lane >> 4, lr = lane & 15;

    f32x4 acc[4][4];
    #pragma unroll
    for (int m = 0; m < 4; m++)
        #pragma unroll
        for (int n = 0; n < 4; n++) acc[m][n] = (f32x4){0.f, 0.f, 0.f, 0.f};

    for (int k0 = 0; k0 < K; k0 += 32) {
        #pragma unroll
        for (int j = 0; j < 2; j++) {
            int cc = j * 256 + wave * 64 + lane;       // 0..511, 8 ushorts each
            int rr = cc >> 2;
            int kp = ((cc & 3) - (rr >> 1)) & 3;       // slot rotation (stage side)
            int gr = row0 + rr; if (gr >= M) gr = M - 1;
            gload16(Abf + (size_t)gr * K + k0 + kp * 8, &As[(j * 256 + wave * 64) * 8]);
            gload16(Wst + (size_t)(col0 + rr) * K + k0 + kp * 8, &Ws[(j * 256 + wave * 64) * 8]);
        }
        __syncthreads();
        bf16x8 af[4], bfr[4];
        #pragma unroll
        for (int m = 0; m < 4; m++) {
            int row = wr * 64 + m * 16 + lr;
            int slot = (g + (row >> 1)) & 3;           // rotation (read side)
            af[m] = *(const bf16x8*)&As[(row * 4 + slot) * 8];
        }
        #pragma unroll
        for (int n = 0; n < 4; n++) {
            int col = wc * 64 + n * 16 + lr;
            int slot = (g + (col >> 1)) & 3;
            bfr[n] = *(const bf16x8*)&Ws[(col * 4 + slot) * 8];
        }
        #pragma unroll
        for (int m = 0; m < 4; m++)
            #pragma unroll
            for (int n = 0; n < 4; n++)
                acc[m][n] = __builtin_amdgcn_mfma_f32_16x16x32_bf16(af[m], bfr[n], acc[m][n], 0, 0, 0);
        __syncthreads();
    }
    #pragma unroll
    for (int m = 0; m < 4; m++) {
        int rowb = row0 + wr * 64 + m * 16 + g * 4;
        #pragma unroll
        for (int n = 0; n < 4; n++) {
            int col = col0 + wc * 64 + n * 16 + lr;
            float b = (col < 256) ? biasL[col] : biasR[col - 256];
            #pragma unroll
            for (int j = 0; j < 4; j++) {
                int grow = rowb + j;
                if (grow < M) Cbf[(size_t)grow * 512 + col] = f2bf(acc[m][n][j] + b);
            }
        }
    }
}

// ================= CSR build =================
__global__ __launch_bounds__(256) void count_deg(
        const int* __restrict__ dst, int* __restrict__ deg) {
    int e = blockIdx.x * 256 + threadIdx.x;
    if (e < EE) atomicAdd(&deg[dst[e]], 1);
}

__global__ __launch_bounds__(256) void scanA(
        const int* __restrict__ deg, int* __restrict__ inc, int* __restrict__ bsum) {
    __shared__ int s[256];
    int i = blockIdx.x * 256 + threadIdx.x;
    int v = (i < NN) ? deg[i] : 0;
    s[threadIdx.x] = v;
    __syncthreads();
    #pragma unroll
    for (int off = 1; off < 256; off <<= 1) {
        int t = (threadIdx.x >= off) ? s[threadIdx.x - off] : 0;
        __syncthreads();
        s[threadIdx.x] += t;
        __syncthreads();
    }
    if (i < NN) inc[i] = s[threadIdx.x];
    if (threadIdx.x == 255) bsum[blockIdx.x] = s[255];
}

__global__ __launch_bounds__(256) void scanB(
        const int* __restrict__ bsum, int* __restrict__ boff, int nblocks) {
    __shared__ int s[256];
    int v = (threadIdx.x < nblocks) ? bsum[threadIdx.x] : 0;
    s[threadIdx.x] = v;
    __syncthreads();
    #pragma unroll
    for (int off = 1; off < 256; off <<= 1) {
        int t = (threadIdx.x >= off) ? s[threadIdx.x - off] : 0;
        __syncthreads();
        s[threadIdx.x] += t;
        __syncthreads();
    }
    if (threadIdx.x < nblocks) boff[threadIdx.x] = s[threadIdx.x] - v;
}

__global__ __launch_bounds__(256) void scanC(
        const int* __restrict__ deg, const int* __restrict__ inc,
        const int* __restrict__ boff,
        int* __restrict__ rowptr, int* __restrict__ wptr) {
    int i = blockIdx.x * 256 + threadIdx.x;
    if (i < NN) {
        int ex = inc[i] - deg[i] + boff[i >> 8];
        rowptr[i] = ex;
        wptr[i] = ex;
    } else if (i == NN) {
        rowptr[NN] = EE;
    }
}

__global__ __launch_bounds__(256) void scatter_src(
        const int* __restrict__ src, const int* __restrict__ dst,
        int* __restrict__ wptr, int* __restrict__ ssrc) {
    int e = blockIdx.x * 256 + threadIdx.x;
    if (e < EE) {
        int pos = atomicAdd(&wptr[dst[e]], 1);
        ssrc[pos] = src[e];
    }
}

// ================= fused GATv2 node kernel =================
// hb: [N][512] bf16, cols 0-255 = xl, cols 256-511 = xr.
// One wave per node, two 32-lane halves each handling half the edges.
// Lane owns 8 channels (head = (lane&31)>>3). Defer-max online softmax (THR=8).
// MODE 1: out = bf16(relu(agg + bias)) -> out_bf [N][256]
// MODE 2: out = (head-mean(agg) + bias) @ Wout + bout -> out_f [N][2]
template<int MODE>
__global__ __launch_bounds__(256) void gat_node(
        const ushort* __restrict__ hb,
        const float* __restrict__ att,
        const int* __restrict__ rowptr, const int* __restrict__ ssrc,
        const float* __restrict__ bias,
        const float* __restrict__ Wout, const float* __restrict__ bout,
        ushort* __restrict__ out_bf, float* __restrict__ out_f) {
    int node = blockIdx.x * 4 + (threadIdx.x >> 6);
    int lane = threadIdx.x & 63;
    if (node >= NN) return;
    const int half = lane >> 5;
    const int hl = lane & 31;

    const int beg = rowptr[node];
    const int cnt = rowptr[node + 1] - beg;
    const int cntA = (cnt + 1) >> 1;
    const int mybeg = beg + half * cntA;
    const int mycnt = half ? (cnt - cntA) : cntA;

    float rr[8], at[8];
    unpack8(*(const uint4*)(hb + (size_t)node * 512 + 256 + hl * 8), rr);
    {
        const float* pat = att + hl * 8;
        float4 t0 = *(const float4*)pat;
        float4 t1 = *(const float4*)(pat + 4);
        at[0] = t0.x; at[1] = t0.y; at[2] = t0.z; at[3] = t0.w;
        at[4] = t1.x; at[5] = t1.y; at[6] = t1.z; at[7] = t1.w;
    }

    float m = -3.0e38f, den = 0.f;
    float acc[8] = {0.f, 0.f, 0.f, 0.f, 0.f, 0.f, 0.f, 0.f};

    int s = (mycnt > 0) ? ssrc[mybeg] : 0;
    for (int it = 0; it < cntA; it++) {
        const bool valid = (it < mycnt);
        int s_next = ssrc[mybeg + ((it + 1 < mycnt) ? it + 1 : 0)];

        uint4 ud = *(const uint4*)(hb + (size_t)s * 512 + hl * 8);
        float xv[8];
        unpack8(ud, xv);

        float part = 0.f;
        #pragma unroll
        for (int c = 0; c < 8; c++) {
            float v = xv[c] + rr[c];
            float lk = fmaxf(v, NEG_SLOPE * v);
            part = fmaf(lk, at[c], part);
        }
        part += __shfl_xor(part, 1, 64);
        part += __shfl_xor(part, 2, 64);
        part += __shfl_xor(part, 4, 64);           // head logit in 8-lane group

        float lg = valid ? part : -3.0e38f;
        if (lg > m + 8.0f) {                       // rare after first edge (defer-max)
            float corr = __expf(m - lg);
            den *= corr;
            #pragma unroll
            for (int c = 0; c < 8; c++) acc[c] *= corr;
            m = lg;
        }
        float p = valid ? __expf(lg - m) : 0.f;    // bounded by e^8
        den += p;
        #pragma unroll
        for (int c = 0; c < 8; c++) acc[c] = fmaf(p, xv[c], acc[c]);
        s = s_next;
    }

    // merge the two half-wave streams
    float m2 = __shfl_xor(m, 32, 64);
    float den2 = __shfl_xor(den, 32, 64);
    float mn = fmaxf(m, m2);
    float cA = __expf(m - mn);
    float cB = __expf(m2 - mn);
    float dtot = fmaf(den, cA, den2 * cB);
    float inv = dtot > 0.f ? 1.0f / dtot : 0.f;
    float o[8];
    #pragma unroll
    for (int c = 0; c < 8; c++) {
        float other = __shfl_xor(acc[c], 32, 64);
        o[c] = fmaf(acc[c], cA, other * cB) * inv;
    }

    if (MODE == 1) {
        // bias + relu -> bf16, packed [N][256]; half 0 writes 16B
        uint4 ow;
        float t0, t1;
        t0 = o[0] + bias[hl * 8 + 0]; t0 = t0 > 0.f ? t0 : 0.f;
        t1 = o[1] + bias[hl * 8 + 1]; t1 = t1 > 0.f ? t1 : 0.f;
        ow.x = (unsigned)f2bf(t0) | ((unsigned)f2bf(t1) << 16);
        t0 = o[2] + bias[hl * 8 + 2]; t0 = t0 > 0.f ? t0 : 0.f;
        t1 = o[3] + bias[hl * 8 + 3]; t1 = t1 > 0.f ? t1 : 0.f;
        ow.y = (unsigned)f2bf(t0) | ((unsigned)f2bf(t1) << 16);
        t0 = o[4] + bias[hl * 8 + 4]; t0 = t0 > 0.f ? t0 : 0.f;
        t1 = o[5] + bias[hl * 8 + 5]; t1 = t1 > 0.f ? t1 : 0.f;
        ow.z = (unsigned)f2bf(t0) | ((unsigned)f2bf(t1) << 16);
        t0 = o[6] + bias[hl * 8 + 6]; t0 = t0 > 0.f ? t0 : 0.f;
        t1 = o[7] + bias[hl * 8 + 7]; t1 = t1 > 0.f ? t1 : 0.f;
        ow.w = (unsigned)f2bf(t0) | ((unsigned)f2bf(t1) << 16);
        if (half == 0)
            *(uint4*)(out_bf + (size_t)node * 256 + hl * 8) = ow;
    } else {
        // head-mean (+ over lanes hl^8, hl^16) + bias2, then @ Wout + bout
        #pragma unroll
        for (int c = 0; c < 8; c++) {
            o[c] += __shfl_xor(o[c], 8, 64);
            o[c] += __shfl_xor(o[c], 16, 64);
        }
        int c64 = (hl & 7) * 8;
        float o0 = 0.f, o1 = 0.f;
        #pragma unroll
        for (int c = 0; c < 8; c++) {
            float t = 0.25f * o[c] + bias[c64 + c];
            o0 = fmaf(t, Wout[(c64 + c) * 2 + 0], o0);
            o1 = fmaf(t, Wout[(c64 + c) * 2 + 1], o1);
        }
        o0 += __shfl_xor(o0, 1, 64); o1 += __shfl_xor(o1, 1, 64);
        o0 += __shfl_xor(o0, 2, 64); o1 += __shfl_xor(o1, 2, 64);
        o0 += __shfl_xor(o0, 4, 64); o1 += __shfl_xor(o1, 4, 64);
        if (lane == 0) {
            out_f[(size_t)node * 2 + 0] = o0 + bout[0];
            out_f[(size_t)node * 2 + 1] = o1 + bout[1];
        }
    }
}

extern "C" void kernel_launch(void* const* d_in, const int* in_sizes, int n_in,
                              void* d_out, int out_size, void* d_ws, size_t ws_size,
                              hipStream_t stream) {
    const float* x     = (const float*)d_in[0];
    const int*   ei    = (const int*)d_in[1];
    const float* Wl1   = (const float*)d_in[2];
    const float* bl1   = (const float*)d_in[3];
    const float* Wr1   = (const float*)d_in[4];
    const float* br1   = (const float*)d_in[5];
    const float* att1  = (const float*)d_in[6];
    const float* bias1 = (const float*)d_in[7];
    const float* Wl2   = (const float*)d_in[8];
    const float* bl2   = (const float*)d_in[9];
    const float* Wr2   = (const float*)d_in[10];
    const float* br2   = (const float*)d_in[11];
    const float* att2  = (const float*)d_in[12];
    const float* bias2 = (const float*)d_in[13];
    const float* Wout  = (const float*)d_in[14];
    const float* bout  = (const float*)d_in[15];

    const int* src = ei;
    const int* dst = ei + EE;

    // ---------- workspace layout ----------
    ushort* hb    = (ushort*)d_ws;                     // [N][512] bf16 (xl|xr)
    ushort* h1_bf = hb + (size_t)NN * 512;             // [N][256] bf16
    ushort* x_bf  = h1_bf + (size_t)NN * 256;          // [N][128] bf16
    ushort* Wst1  = x_bf + (size_t)NN * DIN;           // [512][128]
    ushort* Wst2  = Wst1 + 512 * DIN;                  // [512][256]
    int* deg    = (int*)(Wst2 + 512 * 256);
    int* inc    = deg + NN;
    int* rowptr = inc + NN;                            // NN+1
    int* wptr   = rowptr + NN + 1;
    int* ssrc   = wptr + NN;                           // E
    int* bsum   = ssrc + EE;                           // 256
    int* boff   = bsum + 256;

    const int scanBlocks = (NN + 255) / 256;
    const int edgeBlocks = (EE + 255) / 256;
    const int nodeBlocks = (NN + 3) / 4;
    dim3 gemmGrid((NN + 127) / 128, 4);

    // ---------- CSR build ----------
    hipMemsetAsync(deg, 0, NN * sizeof(int), stream);
    count_deg<<<edgeBlocks, 256, 0, stream>>>(dst, deg);
    scanA<<<scanBlocks, 256, 0, stream>>>(deg, inc, bsum);
    scanB<<<1, 256, 0, stream>>>(bsum, boff, scanBlocks);
    scanC<<<scanBlocks + 1, 256, 0, stream>>>(deg, inc, boff, rowptr, wptr);
    scatter_src<<<edgeBlocks, 256, 0, stream>>>(src, dst, wptr, ssrc);

    // ---------- converts ----------
    cvt_bf16<<<(NN * DIN / 4 + 255) / 256, 256, 0, stream>>>(x, x_bf, NN * DIN / 4);
    cvtT<<<(DIN * 256 + 255) / 256, 256, 0, stream>>>(Wl1, Wst1, DIN);
    cvtT<<<(DIN * 256 + 255) / 256, 256, 0, stream>>>(Wr1, Wst1 + 256 * DIN, DIN);
    cvtT<<<(256 * 256 + 255) / 256, 256, 0, stream>>>(Wl2, Wst2, 256);
    cvtT<<<(256 * 256 + 255) / 256, 256, 0, stream>>>(Wr2, Wst2 + 256 * 256, 256);

    // ---------- layer 1 ----------
    gemm_mfma2<<<gemmGrid, 256, 0, stream>>>(x_bf, Wst1, bl1, br1, hb, NN, DIN);
    gat_node<1><<<nodeBlocks, 256, 0, stream>>>(hb, att1, rowptr, ssrc,
                                                bias1, nullptr, nullptr, h1_bf, nullptr);

    // ---------- layer 2 ----------
    gemm_mfma2<<<gemmGrid, 256, 0, stream>>>(h1_bf, Wst2, bl2, br2, hb, NN, 256);
    gat_node<2><<<nodeBlocks, 256, 0, stream>>>(hb, att2, rowptr, ssrc,
                                                bias2, Wout, bout, nullptr, (float*)d_out);
}

// Round 7
// 308.718 us; speedup vs baseline: 7.5561x; 1.0842x over previous
//
#include <hip/hip_runtime.h>
#include <math.h>

#define NN 50000
#define EE 800000
#define DIN 128
#define F1 256          // HEADS*HID
#define NEG_SLOPE 0.2f

typedef _Float16 half8 __attribute__((ext_vector_type(8)));
typedef _Float16 h2 __attribute__((ext_vector_type(2)));
typedef float f32x4 __attribute__((ext_vector_type(4)));

#if __has_builtin(__builtin_amdgcn_fdot2)
#define FDOT2(a, b, c) __builtin_amdgcn_fdot2((a), (b), (c), false)
#else
#define FDOT2(a, b, c) ((float)(a)[0] * (float)(b)[0] + ((float)(a)[1] * (float)(b)[1] + (c)))
#endif

__device__ __forceinline__ ushort f2h(float f) {
    _Float16 h = (_Float16)f;
    return __builtin_bit_cast(ushort, h);
}

__device__ __forceinline__ void gload16(const void* g, void* l) {
    __builtin_amdgcn_global_load_lds(
        (const __attribute__((address_space(1))) void*)g,
        (__attribute__((address_space(3))) void*)l, 16, 0, 0);
}

// ================= prep: count degrees + convert x and weights to fp16 =================
// ranges: [0,EE) count_deg; [EE, EE+NX8) x->fp16 (8 elems each);
//         [EE+NX8, ...) weight transpose-convert
#define NX8 (NN * DIN / 8)      // 800000
#define W1SZ (512 * DIN)        // 65536
#define W2SZ (512 * 256)        // 131072
__global__ __launch_bounds__(256) void prep(
        const int* __restrict__ dst, int* __restrict__ deg,
        const float* __restrict__ x, ushort* __restrict__ xh,
        const float* __restrict__ Wl1, const float* __restrict__ Wr1,
        const float* __restrict__ Wl2, const float* __restrict__ Wr2,
        ushort* __restrict__ Wst1, ushort* __restrict__ Wst2) {
    int idx = blockIdx.x * 256 + threadIdx.x;
    if (idx < EE) {
        atomicAdd(&deg[dst[idx]], 1);
    } else if (idx < EE + NX8) {
        int i = idx - EE;
        float4 v0 = *(const float4*)(x + (size_t)i * 8);
        float4 v1 = *(const float4*)(x + (size_t)i * 8 + 4);
        ushort4 o0, o1;
        o0.x = f2h(v0.x); o0.y = f2h(v0.y); o0.z = f2h(v0.z); o0.w = f2h(v0.w);
        o1.x = f2h(v1.x); o1.y = f2h(v1.y); o1.z = f2h(v1.z); o1.w = f2h(v1.w);
        *(ushort4*)(xh + (size_t)i * 8) = o0;
        *(ushort4*)(xh + (size_t)i * 8 + 4) = o1;
    } else {
        int j = idx - EE - NX8;
        if (j < W1SZ) {
            int n = j >> 7, k = j & 127;        // Wst1[n][k], K=128
            float v = (n < 256) ? Wl1[(size_t)k * 256 + n] : Wr1[(size_t)k * 256 + (n - 256)];
            Wst1[j] = f2h(v);
        } else if (j < W1SZ + W2SZ) {
            int jj = j - W1SZ;
            int n = jj >> 8, k = jj & 255;      // Wst2[n][k], K=256
            float v = (n < 256) ? Wl2[(size_t)k * 256 + n] : Wr2[(size_t)k * 256 + (n - 256)];
            Wst2[jj] = f2h(v);
        }
    }
}

// ================= fused fp16 MFMA GEMM: C[M,512] = A[M,K] @ [Wl;Wr]^T + bias =================
__global__ __launch_bounds__(256) void gemm_mfma2(
        const ushort* __restrict__ Ah, const ushort* __restrict__ Wst,
        const float* __restrict__ biasL, const float* __restrict__ biasR,
        ushort* __restrict__ Ch, int M, int K) {
    __shared__ ushort As[128 * 32];   // [row][slot*8]  (slot-rotated)
    __shared__ ushort Ws[128 * 32];   // [col][slot*8]
    const int tid = threadIdx.x;
    const int wave = tid >> 6, lane = tid & 63;
    const int row0 = blockIdx.x * 128;
    const int col0 = blockIdx.y * 128;          // 0..3 -> 512 cols
    const int wr = wave >> 1, wc = wave & 1;
    const int g = lane >> 4, lr = lane & 15;

    f32x4 acc[4][4];
    #pragma unroll
    for (int m = 0; m < 4; m++)
        #pragma unroll
        for (int n = 0; n < 4; n++) acc[m][n] = (f32x4){0.f, 0.f, 0.f, 0.f};

    for (int k0 = 0; k0 < K; k0 += 32) {
        #pragma unroll
        for (int j = 0; j < 2; j++) {
            int cc = j * 256 + wave * 64 + lane;       // 0..511, 8 ushorts each
            int rr = cc >> 2;
            int kp = ((cc & 3) - (rr >> 1)) & 3;       // slot rotation (stage side)
            int gr = row0 + rr; if (gr >= M) gr = M - 1;
            gload16(Ah + (size_t)gr * K + k0 + kp * 8, &As[(j * 256 + wave * 64) * 8]);
            gload16(Wst + (size_t)(col0 + rr) * K + k0 + kp * 8, &Ws[(j * 256 + wave * 64) * 8]);
        }
        __syncthreads();
        half8 af[4], bfr[4];
        #pragma unroll
        for (int m = 0; m < 4; m++) {
            int row = wr * 64 + m * 16 + lr;
            int slot = (g + (row >> 1)) & 3;           // rotation (read side)
            af[m] = *(const half8*)&As[(row * 4 + slot) * 8];
        }
        #pragma unroll
        for (int n = 0; n < 4; n++) {
            int col = wc * 64 + n * 16 + lr;
            int slot = (g + (col >> 1)) & 3;
            bfr[n] = *(const half8*)&Ws[(col * 4 + slot) * 8];
        }
        #pragma unroll
        for (int m = 0; m < 4; m++)
            #pragma unroll
            for (int n = 0; n < 4; n++)
                acc[m][n] = __builtin_amdgcn_mfma_f32_16x16x32_f16(af[m], bfr[n], acc[m][n], 0, 0, 0);
        __syncthreads();
    }
    #pragma unroll
    for (int m = 0; m < 4; m++) {
        int rowb = row0 + wr * 64 + m * 16 + g * 4;
        #pragma unroll
        for (int n = 0; n < 4; n++) {
            int col = col0 + wc * 64 + n * 16 + lr;
            float b = (col < 256) ? biasL[col] : biasR[col - 256];
            #pragma unroll
            for (int j = 0; j < 4; j++) {
                int grow = rowb + j;
                if (grow < M) Ch[(size_t)grow * 512 + col] = f2h(acc[m][n][j] + b);
            }
        }
    }
}

// ================= CSR scan kernels =================
__global__ __launch_bounds__(256) void scanA(
        const int* __restrict__ deg, int* __restrict__ inc, int* __restrict__ bsum) {
    __shared__ int s[256];
    int i = blockIdx.x * 256 + threadIdx.x;
    int v = (i < NN) ? deg[i] : 0;
    s[threadIdx.x] = v;
    __syncthreads();
    #pragma unroll
    for (int off = 1; off < 256; off <<= 1) {
        int t = (threadIdx.x >= off) ? s[threadIdx.x - off] : 0;
        __syncthreads();
        s[threadIdx.x] += t;
        __syncthreads();
    }
    if (i < NN) inc[i] = s[threadIdx.x];
    if (threadIdx.x == 255) bsum[blockIdx.x] = s[255];
}

__global__ __launch_bounds__(256) void scanB(
        const int* __restrict__ bsum, int* __restrict__ boff, int nblocks) {
    __shared__ int s[256];
    int v = (threadIdx.x < nblocks) ? bsum[threadIdx.x] : 0;
    s[threadIdx.x] = v;
    __syncthreads();
    #pragma unroll
    for (int off = 1; off < 256; off <<= 1) {
        int t = (threadIdx.x >= off) ? s[threadIdx.x - off] : 0;
        __syncthreads();
        s[threadIdx.x] += t;
        __syncthreads();
    }
    if (threadIdx.x < nblocks) boff[threadIdx.x] = s[threadIdx.x] - v;
}

__global__ __launch_bounds__(256) void scanC(
        const int* __restrict__ deg, const int* __restrict__ inc,
        const int* __restrict__ boff,
        int* __restrict__ rowptr, int* __restrict__ wptr) {
    int i = blockIdx.x * 256 + threadIdx.x;
    if (i < NN) {
        int ex = inc[i] - deg[i] + boff[i >> 8];
        rowptr[i] = ex;
        wptr[i] = ex;
    } else if (i == NN) {
        rowptr[NN] = EE;
    }
}

__global__ __launch_bounds__(256) void scatter_src(
        const int* __restrict__ src, const int* __restrict__ dst,
        int* __restrict__ wptr, int* __restrict__ ssrc) {
    int e = blockIdx.x * 256 + threadIdx.x;
    if (e < EE) {
        int pos = atomicAdd(&wptr[dst[e]], 1);
        ssrc[pos] = src[e];
    }
}

// ================= fused GATv2 node kernel (fp16 packed edge math) =================
// hb: [N][512] fp16, cols 0-255 = xl, cols 256-511 = xr.
// One wave per node, two 32-lane halves each handling half the edges.
// Lane owns 8 channels (head = (lane&31)>>3). Plain-exp softmax (logits bounded).
// MODE 1: out = fp16(relu(agg + bias)) -> out_h [N][256]
// MODE 2: out = (head-mean(agg) + bias) @ Wout + bout -> out_f [N][2]
template<int MODE>
__global__ __launch_bounds__(256) void gat_node(
        const ushort* __restrict__ hb,
        const float* __restrict__ att,
        const int* __restrict__ rowptr, const int* __restrict__ ssrc,
        const float* __restrict__ bias,
        const float* __restrict__ Wout, const float* __restrict__ bout,
        ushort* __restrict__ out_h, float* __restrict__ out_f) {
    int node = blockIdx.x * 4 + (threadIdx.x >> 6);
    int lane = threadIdx.x & 63;
    if (node >= NN) return;
    const int half = lane >> 5;
    const int hl = lane & 31;

    const int beg = rowptr[node];
    const int cnt = rowptr[node + 1] - beg;
    const int cntA = (cnt + 1) >> 1;
    const int mybeg = beg + half * cntA;
    const int mycnt = half ? (cnt - cntA) : cntA;

    const h2 nsh = { (_Float16)NEG_SLOPE, (_Float16)NEG_SLOPE };

    // xr (fp16 packed) and att (converted to fp16 pairs)
    h2 rrh[4], ath[4];
    {
        uint4 ur = *(const uint4*)(hb + (size_t)node * 512 + 256 + hl * 8);
        rrh[0] = __builtin_bit_cast(h2, ur.x);
        rrh[1] = __builtin_bit_cast(h2, ur.y);
        rrh[2] = __builtin_bit_cast(h2, ur.z);
        rrh[3] = __builtin_bit_cast(h2, ur.w);
        const float* pat = att + hl * 8;
        #pragma unroll
        for (int k2 = 0; k2 < 4; k2++) {
            h2 t; t[0] = (_Float16)pat[k2 * 2]; t[1] = (_Float16)pat[k2 * 2 + 1];
            ath[k2] = t;
        }
    }

    float den = 0.f;
    float acc[8] = {0.f, 0.f, 0.f, 0.f, 0.f, 0.f, 0.f, 0.f};

    int s = (mycnt > 0) ? ssrc[mybeg] : 0;
    for (int it = 0; it < cntA; it++) {
        const bool valid = (it < mycnt);
        int s_next = ssrc[mybeg + ((it + 1 < mycnt) ? it + 1 : 0)];

        uint4 ud = *(const uint4*)(hb + (size_t)s * 512 + hl * 8);
        h2 xh[4];
        xh[0] = __builtin_bit_cast(h2, ud.x);
        xh[1] = __builtin_bit_cast(h2, ud.y);
        xh[2] = __builtin_bit_cast(h2, ud.z);
        xh[3] = __builtin_bit_cast(h2, ud.w);

        float part = 0.f;
        #pragma unroll
        for (int k2 = 0; k2 < 4; k2++) {
            h2 v = xh[k2] + rrh[k2];                       // v_pk_add_f16
            h2 lk = __builtin_elementwise_max(v, v * nsh); // v_pk_mul + v_pk_max
            part = FDOT2(lk, ath[k2], part);               // v_dot2_f32_f16
        }
        part += __shfl_xor(part, 1, 64);
        part += __shfl_xor(part, 2, 64);
        part += __shfl_xor(part, 4, 64);                   // head logit in 8-lane group

        float p = valid ? __expf(part) : 0.f;              // logits bounded, no max needed
        den += p;
        #pragma unroll
        for (int k2 = 0; k2 < 4; k2++) {
            acc[k2 * 2 + 0] = fmaf(p, (float)xh[k2][0], acc[k2 * 2 + 0]);
            acc[k2 * 2 + 1] = fmaf(p, (float)xh[k2][1], acc[k2 * 2 + 1]);
        }
        s = s_next;
    }

    // merge the two half-wave streams
    den += __shfl_xor(den, 32, 64);
    float inv = den > 0.f ? 1.0f / den : 0.f;
    float o[8];
    #pragma unroll
    for (int c = 0; c < 8; c++) {
        float t = acc[c] + __shfl_xor(acc[c], 32, 64);
        o[c] = t * inv;
    }

    if (MODE == 1) {
        // bias + relu -> fp16, packed [N][256]; half 0 writes 16B
        uint4 ow;
        float t0, t1;
        t0 = o[0] + bias[hl * 8 + 0]; t0 = t0 > 0.f ? t0 : 0.f;
        t1 = o[1] + bias[hl * 8 + 1]; t1 = t1 > 0.f ? t1 : 0.f;
        ow.x = (unsigned)f2h(t0) | ((unsigned)f2h(t1) << 16);
        t0 = o[2] + bias[hl * 8 + 2]; t0 = t0 > 0.f ? t0 : 0.f;
        t1 = o[3] + bias[hl * 8 + 3]; t1 = t1 > 0.f ? t1 : 0.f;
        ow.y = (unsigned)f2h(t0) | ((unsigned)f2h(t1) << 16);
        t0 = o[4] + bias[hl * 8 + 4]; t0 = t0 > 0.f ? t0 : 0.f;
        t1 = o[5] + bias[hl * 8 + 5]; t1 = t1 > 0.f ? t1 : 0.f;
        ow.z = (unsigned)f2h(t0) | ((unsigned)f2h(t1) << 16);
        t0 = o[6] + bias[hl * 8 + 6]; t0 = t0 > 0.f ? t0 : 0.f;
        t1 = o[7] + bias[hl * 8 + 7]; t1 = t1 > 0.f ? t1 : 0.f;
        ow.w = (unsigned)f2h(t0) | ((unsigned)f2h(t1) << 16);
        if (half == 0)
            *(uint4*)(out_h + (size_t)node * 256 + hl * 8) = ow;
    } else {
        // head-mean (lanes hl^8, hl^16) + bias2, then @ Wout + bout
        #pragma unroll
        for (int c = 0; c < 8; c++) {
            o[c] += __shfl_xor(o[c], 8, 64);
            o[c] += __shfl_xor(o[c], 16, 64);
        }
        int c64 = (hl & 7) * 8;
        float o0 = 0.f, o1 = 0.f;
        #pragma unroll
        for (int c = 0; c < 8; c++) {
            float t = 0.25f * o[c] + bias[c64 + c];
            o0 = fmaf(t, Wout[(c64 + c) * 2 + 0], o0);
            o1 = fmaf(t, Wout[(c64 + c) * 2 + 1], o1);
        }
        o0 += __shfl_xor(o0, 1, 64); o1 += __shfl_xor(o1, 1, 64);
        o0 += __shfl_xor(o0, 2, 64); o1 += __shfl_xor(o1, 2, 64);
        o0 += __shfl_xor(o0, 4, 64); o1 += __shfl_xor(o1, 4, 64);
        if (lane == 0) {
            out_f[(size_t)node * 2 + 0] = o0 + bout[0];
            out_f[(size_t)node * 2 + 1] = o1 + bout[1];
        }
    }
}

extern "C" void kernel_launch(void* const* d_in, const int* in_sizes, int n_in,
                              void* d_out, int out_size, void* d_ws, size_t ws_size,
                              hipStream_t stream) {
    const float* x     = (const float*)d_in[0];
    const int*   ei    = (const int*)d_in[1];
    const float* Wl1   = (const float*)d_in[2];
    const float* bl1   = (const float*)d_in[3];
    const float* Wr1   = (const float*)d_in[4];
    const float* br1   = (const float*)d_in[5];
    const float* att1  = (const float*)d_in[6];
    const float* bias1 = (const float*)d_in[7];
    const float* Wl2   = (const float*)d_in[8];
    const float* bl2   = (const float*)d_in[9];
    const float* Wr2   = (const float*)d_in[10];
    const float* br2   = (const float*)d_in[11];
    const float* att2  = (const float*)d_in[12];
    const float* bias2 = (const float*)d_in[13];
    const float* Wout  = (const float*)d_in[14];
    const float* bout  = (const float*)d_in[15];

    const int* src = ei;
    const int* dst = ei + EE;

    // ---------- workspace layout ----------
    ushort* hb    = (ushort*)d_ws;                     // [N][512] fp16 (xl|xr)
    ushort* h1_h  = hb + (size_t)NN * 512;             // [N][256] fp16
    ushort* xh    = h1_h + (size_t)NN * 256;           // [N][128] fp16
    ushort* Wst1  = xh + (size_t)NN * DIN;             // [512][128]
    ushort* Wst2  = Wst1 + W1SZ;                       // [512][256]
    int* deg    = (int*)(Wst2 + W2SZ);
    int* inc    = deg + NN;
    int* rowptr = inc + NN;                            // NN+1
    int* wptr   = rowptr + NN + 1;
    int* ssrc   = wptr + NN;                           // E
    int* bsum   = ssrc + EE;                           // 256
    int* boff   = bsum + 256;

    const int scanBlocks = (NN + 255) / 256;
    const int edgeBlocks = (EE + 255) / 256;
    const int nodeBlocks = (NN + 3) / 4;
    const int prepBlocks = (EE + NX8 + W1SZ + W2SZ + 255) / 256;
    dim3 gemmGrid((NN + 127) / 128, 4);

    // ---------- CSR build + converts ----------
    hipMemsetAsync(deg, 0, NN * sizeof(int), stream);
    prep<<<prepBlocks, 256, 0, stream>>>(dst, deg, x, xh, Wl1, Wr1, Wl2, Wr2, Wst1, Wst2);
    scanA<<<scanBlocks, 256, 0, stream>>>(deg, inc, bsum);
    scanB<<<1, 256, 0, stream>>>(bsum, boff, scanBlocks);
    scanC<<<scanBlocks + 1, 256, 0, stream>>>(deg, inc, boff, rowptr, wptr);
    scatter_src<<<edgeBlocks, 256, 0, stream>>>(src, dst, wptr, ssrc);

    // ---------- layer 1 ----------
    gemm_mfma2<<<gemmGrid, 256, 0, stream>>>(xh, Wst1, bl1, br1, hb, NN, DIN);
    gat_node<1><<<nodeBlocks, 256, 0, stream>>>(hb, att1, rowptr, ssrc,
                                                bias1, nullptr, nullptr, h1_h, nullptr);

    // ---------- layer 2 ----------
    gemm_mfma2<<<gemmGrid, 256, 0, stream>>>(h1_h, Wst2, bl2, br2, hb, NN, 256);
    gat_node<2><<<nodeBlocks, 256, 0, stream>>>(hb, att2, rowptr, ssrc,
                                                bias2, Wout, bout, nullptr, (float*)d_out);
}

// Round 8
// 304.172 us; speedup vs baseline: 7.6691x; 1.0149x over previous
//
#include <hip/hip_runtime.h>
#include <math.h>

#define NN 50000
#define EE 800000
#define DIN 128
#define F1 256          // HEADS*HID
#define NEG_SLOPE 0.2f

typedef _Float16 half8 __attribute__((ext_vector_type(8)));
typedef _Float16 h2 __attribute__((ext_vector_type(2)));
typedef float f32x4 __attribute__((ext_vector_type(4)));

#if __has_builtin(__builtin_amdgcn_fdot2)
#define FDOT2(a, b, c) __builtin_amdgcn_fdot2((a), (b), (c), false)
#else
#define FDOT2(a, b, c) ((float)(a)[0] * (float)(b)[0] + ((float)(a)[1] * (float)(b)[1] + (c)))
#endif

__device__ __forceinline__ ushort f2h(float f) {
    _Float16 h = (_Float16)f;
    return __builtin_bit_cast(ushort, h);
}

__device__ __forceinline__ void gload16(const void* g, void* l) {
    __builtin_amdgcn_global_load_lds(
        (const __attribute__((address_space(1))) void*)g,
        (__attribute__((address_space(3))) void*)l, 16, 0, 0);
}

// ================= prep: count degrees + convert x and weights to fp16 =================
#define NX8 (NN * DIN / 8)      // 800000
#define W1SZ (512 * DIN)        // 65536
#define W2SZ (512 * 256)        // 131072
__global__ __launch_bounds__(256) void prep(
        const int* __restrict__ dst, int* __restrict__ deg,
        const float* __restrict__ x, ushort* __restrict__ xh,
        const float* __restrict__ Wl1, const float* __restrict__ Wr1,
        const float* __restrict__ Wl2, const float* __restrict__ Wr2,
        ushort* __restrict__ Wst1, ushort* __restrict__ Wst2) {
    int idx = blockIdx.x * 256 + threadIdx.x;
    if (idx < EE) {
        atomicAdd(&deg[dst[idx]], 1);
    } else if (idx < EE + NX8) {
        int i = idx - EE;
        float4 v0 = *(const float4*)(x + (size_t)i * 8);
        float4 v1 = *(const float4*)(x + (size_t)i * 8 + 4);
        ushort4 o0, o1;
        o0.x = f2h(v0.x); o0.y = f2h(v0.y); o0.z = f2h(v0.z); o0.w = f2h(v0.w);
        o1.x = f2h(v1.x); o1.y = f2h(v1.y); o1.z = f2h(v1.z); o1.w = f2h(v1.w);
        *(ushort4*)(xh + (size_t)i * 8) = o0;
        *(ushort4*)(xh + (size_t)i * 8 + 4) = o1;
    } else {
        int j = idx - EE - NX8;
        if (j < W1SZ) {
            int n = j >> 7, k = j & 127;        // Wst1[n][k], K=128
            float v = (n < 256) ? Wl1[(size_t)k * 256 + n] : Wr1[(size_t)k * 256 + (n - 256)];
            Wst1[j] = f2h(v);
        } else if (j < W1SZ + W2SZ) {
            int jj = j - W1SZ;
            int n = jj >> 8, k = jj & 255;      // Wst2[n][k], K=256
            float v = (n < 256) ? Wl2[(size_t)k * 256 + n] : Wr2[(size_t)k * 256 + (n - 256)];
            Wst2[jj] = f2h(v);
        }
    }
}

// ================= fused fp16 MFMA GEMM: C[M,512] = A[M,K] @ [Wl;Wr]^T + bias =================
__global__ __launch_bounds__(256) void gemm_mfma2(
        const ushort* __restrict__ Ah, const ushort* __restrict__ Wst,
        const float* __restrict__ biasL, const float* __restrict__ biasR,
        ushort* __restrict__ Ch, int M, int K) {
    __shared__ ushort As[128 * 32];   // [row][slot*8]  (slot-rotated)
    __shared__ ushort Ws[128 * 32];   // [col][slot*8]
    const int tid = threadIdx.x;
    const int wave = tid >> 6, lane = tid & 63;
    const int row0 = blockIdx.x * 128;
    const int col0 = blockIdx.y * 128;          // 0..3 -> 512 cols
    const int wr = wave >> 1, wc = wave & 1;
    const int g = lane >> 4, lr = lane & 15;

    f32x4 acc[4][4];
    #pragma unroll
    for (int m = 0; m < 4; m++)
        #pragma unroll
        for (int n = 0; n < 4; n++) acc[m][n] = (f32x4){0.f, 0.f, 0.f, 0.f};

    for (int k0 = 0; k0 < K; k0 += 32) {
        #pragma unroll
        for (int j = 0; j < 2; j++) {
            int cc = j * 256 + wave * 64 + lane;       // 0..511, 8 ushorts each
            int rr = cc >> 2;
            int kp = ((cc & 3) - (rr >> 1)) & 3;       // slot rotation (stage side)
            int gr = row0 + rr; if (gr >= M) gr = M - 1;
            gload16(Ah + (size_t)gr * K + k0 + kp * 8, &As[(j * 256 + wave * 64) * 8]);
            gload16(Wst + (size_t)(col0 + rr) * K + k0 + kp * 8, &Ws[(j * 256 + wave * 64) * 8]);
        }
        __syncthreads();
        half8 af[4], bfr[4];
        #pragma unroll
        for (int m = 0; m < 4; m++) {
            int row = wr * 64 + m * 16 + lr;
            int slot = (g + (row >> 1)) & 3;           // rotation (read side)
            af[m] = *(const half8*)&As[(row * 4 + slot) * 8];
        }
        #pragma unroll
        for (int n = 0; n < 4; n++) {
            int col = wc * 64 + n * 16 + lr;
            int slot = (g + (col >> 1)) & 3;
            bfr[n] = *(const half8*)&Ws[(col * 4 + slot) * 8];
        }
        #pragma unroll
        for (int m = 0; m < 4; m++)
            #pragma unroll
            for (int n = 0; n < 4; n++)
                acc[m][n] = __builtin_amdgcn_mfma_f32_16x16x32_f16(af[m], bfr[n], acc[m][n], 0, 0, 0);
        __syncthreads();
    }
    #pragma unroll
    for (int m = 0; m < 4; m++) {
        int rowb = row0 + wr * 64 + m * 16 + g * 4;
        #pragma unroll
        for (int n = 0; n < 4; n++) {
            int col = col0 + wc * 64 + n * 16 + lr;
            float b = (col < 256) ? biasL[col] : biasR[col - 256];
            #pragma unroll
            for (int j = 0; j < 4; j++) {
                int grow = rowb + j;
                if (grow < M) Ch[(size_t)grow * 512 + col] = f2h(acc[m][n][j] + b);
            }
        }
    }
}

// ================= CSR scan kernels =================
__global__ __launch_bounds__(256) void scanA(
        const int* __restrict__ deg, int* __restrict__ inc, int* __restrict__ bsum) {
    __shared__ int s[256];
    int i = blockIdx.x * 256 + threadIdx.x;
    int v = (i < NN) ? deg[i] : 0;
    s[threadIdx.x] = v;
    __syncthreads();
    #pragma unroll
    for (int off = 1; off < 256; off <<= 1) {
        int t = (threadIdx.x >= off) ? s[threadIdx.x - off] : 0;
        __syncthreads();
        s[threadIdx.x] += t;
        __syncthreads();
    }
    if (i < NN) inc[i] = s[threadIdx.x];
    if (threadIdx.x == 255) bsum[blockIdx.x] = s[255];
}

__global__ __launch_bounds__(256) void scanB(
        const int* __restrict__ bsum, int* __restrict__ boff, int nblocks) {
    __shared__ int s[256];
    int v = (threadIdx.x < nblocks) ? bsum[threadIdx.x] : 0;
    s[threadIdx.x] = v;
    __syncthreads();
    #pragma unroll
    for (int off = 1; off < 256; off <<= 1) {
        int t = (threadIdx.x >= off) ? s[threadIdx.x - off] : 0;
        __syncthreads();
        s[threadIdx.x] += t;
        __syncthreads();
    }
    if (threadIdx.x < nblocks) boff[threadIdx.x] = s[threadIdx.x] - v;
}

__global__ __launch_bounds__(256) void scanC(
        const int* __restrict__ deg, const int* __restrict__ inc,
        const int* __restrict__ boff,
        int* __restrict__ rowptr, int* __restrict__ wptr) {
    int i = blockIdx.x * 256 + threadIdx.x;
    if (i < NN) {
        int ex = inc[i] - deg[i] + boff[i >> 8];
        rowptr[i] = ex;
        wptr[i] = ex;
    } else if (i == NN) {
        rowptr[NN] = EE;
    }
}

__global__ __launch_bounds__(256) void scatter_src(
        const int* __restrict__ src, const int* __restrict__ dst,
        int* __restrict__ wptr, int* __restrict__ ssrc) {
    int e = blockIdx.x * 256 + threadIdx.x;
    if (e < EE) {
        int pos = atomicAdd(&wptr[dst[e]], 1);
        ssrc[pos] = src[e];
    }
}

// ================= fused GATv2 node kernel (fp16 packed, 2-edge ILP) =================
// hb: [N][512] fp16, cols 0-255 = xl, cols 256-511 = xr.
// One wave per node, two 32-lane halves; each half processes its edge subset
// TWO edges per iteration (independent gather+logit chains for latency hiding).
// Lane owns 8 channels (head = (lane&31)>>3). Plain-exp softmax (logits bounded).
template<int MODE>
__global__ __launch_bounds__(256) void gat_node(
        const ushort* __restrict__ hb,
        const float* __restrict__ att,
        const int* __restrict__ rowptr, const int* __restrict__ ssrc,
        const float* __restrict__ bias,
        const float* __restrict__ Wout, const float* __restrict__ bout,
        ushort* __restrict__ out_h, float* __restrict__ out_f) {
    int node = blockIdx.x * 4 + (threadIdx.x >> 6);
    int lane = threadIdx.x & 63;
    if (node >= NN) return;
    const int half = lane >> 5;
    const int hl = lane & 31;

    const int beg = rowptr[node];
    const int cnt = rowptr[node + 1] - beg;
    const int cntA = (cnt + 1) >> 1;
    const int mybeg = beg + half * cntA;
    const int mycnt = half ? (cnt - cntA) : cntA;

    const h2 nsh = { (_Float16)NEG_SLOPE, (_Float16)NEG_SLOPE };

    // xr (fp16 packed) and att (converted to fp16 pairs)
    h2 rrh[4], ath[4];
    {
        uint4 ur = *(const uint4*)(hb + (size_t)node * 512 + 256 + hl * 8);
        rrh[0] = __builtin_bit_cast(h2, ur.x);
        rrh[1] = __builtin_bit_cast(h2, ur.y);
        rrh[2] = __builtin_bit_cast(h2, ur.z);
        rrh[3] = __builtin_bit_cast(h2, ur.w);
        const float* pat = att + hl * 8;
        #pragma unroll
        for (int k2 = 0; k2 < 4; k2++) {
            h2 t; t[0] = (_Float16)pat[k2 * 2]; t[1] = (_Float16)pat[k2 * 2 + 1];
            ath[k2] = t;
        }
    }

    float den = 0.f;
    float acc[8] = {0.f, 0.f, 0.f, 0.f, 0.f, 0.f, 0.f, 0.f};

    for (int it = 0; it < cntA; it += 2) {
        const bool v0 = (it < mycnt);
        const bool v1 = (it + 1 < mycnt);
        // invalid slots clamp to beg (valid whenever the loop runs: cntA>0 -> cnt>0)
        int i0 = v0 ? mybeg + it : beg;
        int i1 = v1 ? mybeg + it + 1 : beg;
        int s0 = ssrc[i0];
        int s1 = ssrc[i1];

        uint4 ud0 = *(const uint4*)(hb + (size_t)s0 * 512 + hl * 8);
        uint4 ud1 = *(const uint4*)(hb + (size_t)s1 * 512 + hl * 8);
        h2 xa[4], xb[4];
        xa[0] = __builtin_bit_cast(h2, ud0.x); xb[0] = __builtin_bit_cast(h2, ud1.x);
        xa[1] = __builtin_bit_cast(h2, ud0.y); xb[1] = __builtin_bit_cast(h2, ud1.y);
        xa[2] = __builtin_bit_cast(h2, ud0.z); xb[2] = __builtin_bit_cast(h2, ud1.z);
        xa[3] = __builtin_bit_cast(h2, ud0.w); xb[3] = __builtin_bit_cast(h2, ud1.w);

        float pa = 0.f, pb = 0.f;
        #pragma unroll
        for (int k2 = 0; k2 < 4; k2++) {
            h2 va = xa[k2] + rrh[k2];
            h2 vb = xb[k2] + rrh[k2];
            h2 la = __builtin_elementwise_max(va, va * nsh);
            h2 lb = __builtin_elementwise_max(vb, vb * nsh);
            pa = FDOT2(la, ath[k2], pa);
            pb = FDOT2(lb, ath[k2], pb);
        }
        pa += __shfl_xor(pa, 1, 64); pb += __shfl_xor(pb, 1, 64);
        pa += __shfl_xor(pa, 2, 64); pb += __shfl_xor(pb, 2, 64);
        pa += __shfl_xor(pa, 4, 64); pb += __shfl_xor(pb, 4, 64);

        float p0 = v0 ? __expf(pa) : 0.f;
        float p1 = v1 ? __expf(pb) : 0.f;
        den += p0 + p1;
        #pragma unroll
        for (int k2 = 0; k2 < 4; k2++) {
            acc[k2 * 2 + 0] = fmaf(p0, (float)xa[k2][0], acc[k2 * 2 + 0]);
            acc[k2 * 2 + 1] = fmaf(p0, (float)xa[k2][1], acc[k2 * 2 + 1]);
            acc[k2 * 2 + 0] = fmaf(p1, (float)xb[k2][0], acc[k2 * 2 + 0]);
            acc[k2 * 2 + 1] = fmaf(p1, (float)xb[k2][1], acc[k2 * 2 + 1]);
        }
    }

    // merge the two half-wave streams
    den += __shfl_xor(den, 32, 64);
    float inv = den > 0.f ? 1.0f / den : 0.f;
    float o[8];
    #pragma unroll
    for (int c = 0; c < 8; c++) {
        float t = acc[c] + __shfl_xor(acc[c], 32, 64);
        o[c] = t * inv;
    }

    if (MODE == 1) {
        // bias + relu -> fp16, packed [N][256]; half 0 writes 16B
        uint4 ow;
        float t0, t1;
        t0 = o[0] + bias[hl * 8 + 0]; t0 = t0 > 0.f ? t0 : 0.f;
        t1 = o[1] + bias[hl * 8 + 1]; t1 = t1 > 0.f ? t1 : 0.f;
        ow.x = (unsigned)f2h(t0) | ((unsigned)f2h(t1) << 16);
        t0 = o[2] + bias[hl * 8 + 2]; t0 = t0 > 0.f ? t0 : 0.f;
        t1 = o[3] + bias[hl * 8 + 3]; t1 = t1 > 0.f ? t1 : 0.f;
        ow.y = (unsigned)f2h(t0) | ((unsigned)f2h(t1) << 16);
        t0 = o[4] + bias[hl * 8 + 4]; t0 = t0 > 0.f ? t0 : 0.f;
        t1 = o[5] + bias[hl * 8 + 5]; t1 = t1 > 0.f ? t1 : 0.f;
        ow.z = (unsigned)f2h(t0) | ((unsigned)f2h(t1) << 16);
        t0 = o[6] + bias[hl * 8 + 6]; t0 = t0 > 0.f ? t0 : 0.f;
        t1 = o[7] + bias[hl * 8 + 7]; t1 = t1 > 0.f ? t1 : 0.f;
        ow.w = (unsigned)f2h(t0) | ((unsigned)f2h(t1) << 16);
        if (half == 0)
            *(uint4*)(out_h + (size_t)node * 256 + hl * 8) = ow;
    } else {
        // head-mean (lanes hl^8, hl^16) + bias2, then @ Wout + bout
        #pragma unroll
        for (int c = 0; c < 8; c++) {
            o[c] += __shfl_xor(o[c], 8, 64);
            o[c] += __shfl_xor(o[c], 16, 64);
        }
        int c64 = (hl & 7) * 8;
        float o0 = 0.f, o1 = 0.f;
        #pragma unroll
        for (int c = 0; c < 8; c++) {
            float t = 0.25f * o[c] + bias[c64 + c];
            o0 = fmaf(t, Wout[(c64 + c) * 2 + 0], o0);
            o1 = fmaf(t, Wout[(c64 + c) * 2 + 1], o1);
        }
        o0 += __shfl_xor(o0, 1, 64); o1 += __shfl_xor(o1, 1, 64);
        o0 += __shfl_xor(o0, 2, 64); o1 += __shfl_xor(o1, 2, 64);
        o0 += __shfl_xor(o0, 4, 64); o1 += __shfl_xor(o1, 4, 64);
        if (lane == 0) {
            out_f[(size_t)node * 2 + 0] = o0 + bout[0];
            out_f[(size_t)node * 2 + 1] = o1 + bout[1];
        }
    }
}

extern "C" void kernel_launch(void* const* d_in, const int* in_sizes, int n_in,
                              void* d_out, int out_size, void* d_ws, size_t ws_size,
                              hipStream_t stream) {
    const float* x     = (const float*)d_in[0];
    const int*   ei    = (const int*)d_in[1];
    const float* Wl1   = (const float*)d_in[2];
    const float* bl1   = (const float*)d_in[3];
    const float* Wr1   = (const float*)d_in[4];
    const float* br1   = (const float*)d_in[5];
    const float* att1  = (const float*)d_in[6];
    const float* bias1 = (const float*)d_in[7];
    const float* Wl2   = (const float*)d_in[8];
    const float* bl2   = (const float*)d_in[9];
    const float* Wr2   = (const float*)d_in[10];
    const float* br2   = (const float*)d_in[11];
    const float* att2  = (const float*)d_in[12];
    const float* bias2 = (const float*)d_in[13];
    const float* Wout  = (const float*)d_in[14];
    const float* bout  = (const float*)d_in[15];

    const int* src = ei;
    const int* dst = ei + EE;

    // ---------- workspace layout ----------
    ushort* hb    = (ushort*)d_ws;                     // [N][512] fp16 (xl|xr)
    ushort* h1_h  = hb + (size_t)NN * 512;             // [N][256] fp16
    ushort* xh    = h1_h + (size_t)NN * 256;           // [N][128] fp16
    ushort* Wst1  = xh + (size_t)NN * DIN;             // [512][128]
    ushort* Wst2  = Wst1 + W1SZ;                       // [512][256]
    int* deg    = (int*)(Wst2 + W2SZ);
    int* inc    = deg + NN;
    int* rowptr = inc + NN;                            // NN+1
    int* wptr   = rowptr + NN + 1;
    int* ssrc   = wptr + NN;                           // E
    int* bsum   = ssrc + EE;                           // 256
    int* boff   = bsum + 256;

    const int scanBlocks = (NN + 255) / 256;
    const int edgeBlocks = (EE + 255) / 256;
    const int nodeBlocks = (NN + 3) / 4;
    const int prepBlocks = (EE + NX8 + W1SZ + W2SZ + 255) / 256;
    dim3 gemmGrid((NN + 127) / 128, 4);

    // ---------- CSR build + converts ----------
    hipMemsetAsync(deg, 0, NN * sizeof(int), stream);
    prep<<<prepBlocks, 256, 0, stream>>>(dst, deg, x, xh, Wl1, Wr1, Wl2, Wr2, Wst1, Wst2);
    scanA<<<scanBlocks, 256, 0, stream>>>(deg, inc, bsum);
    scanB<<<1, 256, 0, stream>>>(bsum, boff, scanBlocks);
    scanC<<<scanBlocks + 1, 256, 0, stream>>>(deg, inc, boff, rowptr, wptr);
    scatter_src<<<edgeBlocks, 256, 0, stream>>>(src, dst, wptr, ssrc);

    // ---------- layer 1 ----------
    gemm_mfma2<<<gemmGrid, 256, 0, stream>>>(xh, Wst1, bl1, br1, hb, NN, DIN);
    gat_node<1><<<nodeBlocks, 256, 0, stream>>>(hb, att1, rowptr, ssrc,
                                                bias1, nullptr, nullptr, h1_h, nullptr);

    // ---------- layer 2 ----------
    gemm_mfma2<<<gemmGrid, 256, 0, stream>>>(h1_h, Wst2, bl2, br2, hb, NN, 256);
    gat_node<2><<<nodeBlocks, 256, 0, stream>>>(hb, att2, rowptr, ssrc,
                                                bias2, Wout, bout, nullptr, (float*)d_out);
}